// Round 7
// baseline (201.896 us; speedup 1.0000x reference)
//
#include <hip/hip_runtime.h>
#include <hip/hip_bf16.h>
#include <math.h>

typedef _Float16 f16x8 __attribute__((ext_vector_type(8)));
typedef float f32x4 __attribute__((ext_vector_type(4)));

#define N_TOK 16384
#define D 256
#define K 8192

#define Q_OFF 0
#define IND_OFF 4194304
#define PERP_OFF 4210688
#define COMMIT_OFF 4210689

// ---------- ws layout (bytes) ----------
#define WS_CAND   0u          // u32[16384][16]  (1 MB)
#define WS_E2     1048576u    // f32[8192]
#define WS_DSUM   1081344u    // double
#define WS_EH     1114112u    // f16[8192][256]  (4 MB)
#define WS_XH     5308416u    // f16[16384][256] (8 MB)
#define WS_XT     13697024u   // f32[16384][256] (16 MB)
#define WS_NEED   30474240u

__device__ __forceinline__ unsigned int ford(float f) {
    unsigned int u = __float_as_uint(f);
    return (u & 0x80000000u) ? ~u : (u | 0x80000000u);
}
__device__ __forceinline__ unsigned short f2h(float f) {
    _Float16 h = (_Float16)f;
    return *(unsigned short*)&h;
}
__device__ __forceinline__ void gload16(const void* g, void* l) {
    __builtin_amdgcn_global_load_lds(
        (const __attribute__((address_space(1))) unsigned int*)g,
        (__attribute__((address_space(3))) unsigned int*)l, 16, 0, 0);
}

// ============================ FAST PATH ============================

// transpose x: (b,c,p) f32 -> XT[n][c] f32 and Xh[n][c] f16
__global__ void vq_convert_x(const float* __restrict__ x, float* __restrict__ xt,
                             unsigned short* __restrict__ xh) {
    __shared__ float t[64][65];
    const int tid = threadIdx.x;
    const int p0 = blockIdx.x * 64, c0 = blockIdx.y * 64, b = blockIdx.z;
    const int q = tid & 15, h = tid >> 4;
    #pragma unroll
    for (int r = 0; r < 4; ++r) {
        const int cl = r * 16 + h;
        const float4 v = *(const float4*)(x + (((size_t)(b * 256 + c0 + cl)) << 10) + p0 + q * 4);
        t[cl][q * 4 + 0] = v.x; t[cl][q * 4 + 1] = v.y;
        t[cl][q * 4 + 2] = v.z; t[cl][q * 4 + 3] = v.w;
    }
    __syncthreads();
    #pragma unroll
    for (int r = 0; r < 4; ++r) {
        const int nl = r * 16 + h;
        const int n = (b << 10) + p0 + nl;
        const int c = c0 + q * 4;
        float4 vf; ushort4 vh;
        vf.x = t[q * 4 + 0][nl]; vf.y = t[q * 4 + 1][nl];
        vf.z = t[q * 4 + 2][nl]; vf.w = t[q * 4 + 3][nl];
        vh.x = f2h(vf.x); vh.y = f2h(vf.y); vh.z = f2h(vf.z); vh.w = f2h(vf.w);
        *(float4*)(xt + ((size_t)n << 8) + c) = vf;
        *(ushort4*)(xh + ((size_t)n << 8) + c) = vh;
    }
}

// fused: embed -> f16, e2 row norms, dsum init. one wave per code row.
__global__ void vq_prep_e(const float* __restrict__ e, unsigned short* __restrict__ eh,
                          float* __restrict__ e2, double* __restrict__ dsum) {
    if (blockIdx.x == 0 && threadIdx.x == 0) *dsum = 0.0;
    const int wave = threadIdx.x >> 6, lane = threadIdx.x & 63;
    const int c = blockIdx.x * 4 + wave;
    const float4 v = *(const float4*)(e + (size_t)c * D + lane * 4);
    ushort4 vh;
    vh.x = f2h(v.x); vh.y = f2h(v.y); vh.z = f2h(v.z); vh.w = f2h(v.w);
    *(ushort4*)(eh + (size_t)c * D + lane * 4) = vh;
    float s = v.x * v.x + v.y * v.y + v.z * v.z + v.w * v.w;
    #pragma unroll
    for (int off = 32; off > 0; off >>= 1) s += __shfl_down(s, off, 64);
    if (lane == 0) e2[c] = s;
}

// fp16 screen GEMM + per-split top-2.
// grid (64 M-tiles, 8 splits) = 512 blocks (2/CU), 256 threads (4 waves).
// A panel: 64 rows x 256 K per wave in REGISTERS (pinned via asm).
// B: wave-PRIVATE LDS triple buffer, 3 x 4KB/wave; ZERO barriers in the hot
// loop — ordering via counted s_waitcnt vmcnt(8) (3-deep pipeline, T3+T4).
__global__ __launch_bounds__(256, 2) void vq_mfma_kernel(
    const unsigned short* __restrict__ xh, const unsigned short* __restrict__ eh,
    const float* __restrict__ e2, unsigned int* __restrict__ cand) {
    __shared__ __align__(16) unsigned short Bs[4][3][2048];  // 48 KB
    __shared__ float e2s[1024];                               // 4 KB

    const int tid = threadIdx.x;
    const int lane = tid & 63, wid = tid >> 6;
    const int l15 = lane & 15, lg = lane >> 4;
    const int split = blockIdx.y;
    const int m0 = blockIdx.x * 256;
    const int c0s = split * 1024;
    const int rw = m0 + wid * 64;  // wave's first token row
    char* wb = (char*)&Bs[wid][0][0];

    // e2 slice -> LDS (keeps vmcnt clean inside the hot loop)
    *(float4*)&e2s[tid * 4] = *(const float4*)(e2 + c0s + tid * 4);
    __syncthreads();

    // ---- A fragments: 64 rows x 256 K in registers (one-time global load) ----
    f16x8 a[4][8];
    #pragma unroll
    for (int mf = 0; mf < 4; ++mf) {
        const unsigned short* ap = xh + (((size_t)(rw + mf * 16 + l15)) << 8) + lg * 8;
        #pragma unroll
        for (int t = 0; t < 8; ++t)
            a[mf][t] = *(const f16x8*)(ap + t * 32);
    }
    // pin A in registers: opaque modify forbids rematerializing the loads
    #pragma unroll
    for (int mf = 0; mf < 4; ++mf)
        #pragma unroll
        for (int t = 0; t < 8; ++t)
            asm volatile("" : "+v"(*(f32x4*)&a[mf][t]));

    // stage one 32-code x 64-k B tile (4KB) into this wave's buffer at byte
    // offset bo. source col pre-swizzled, LDS linear (rule #21).
    auto stage = [&](int s, int bo) {
        const int c0 = c0s + (s >> 2) * 32;
        const int kk = (s & 3) * 64;
        #pragma unroll
        for (int i = 0; i < 4; ++i) {
            const int chunk = i * 64 + lane;
            const int r = chunk >> 3, cl = chunk & 7;
            gload16(eh + (((size_t)(c0 + r)) << 8) + kk + ((cl ^ (r & 7)) << 3),
                    wb + bo + i * 1024);
        }
    };

    // B fragment read byte offsets (XOR-swizzled), relative to buffer base
    int boff[2][2];
    #pragma unroll
    for (int nf = 0; nf < 2; ++nf)
        #pragma unroll
        for (int ks2 = 0; ks2 < 2; ++ks2) {
            const int rb = nf * 16 + l15;
            boff[nf][ks2] = rb * 128 + (((ks2 * 4 + lg) ^ (rb & 7)) << 4);
        }

    float d1[16], d2[16];
    unsigned int ipk[16];
    #pragma unroll
    for (int r = 0; r < 16; ++r) { d1[r] = INFINITY; d2[r] = INFINITY; ipk[r] = 0; }

    int bo0 = 0, bo1 = 4096, bo2 = 8192;
    stage(0, bo0);
    stage(1, bo1);

    #pragma unroll 1
    for (int ct = 0; ct < 32; ++ct) {
        const float e2v0 = e2s[ct * 32 + l15];
        const float e2v1 = e2s[ct * 32 + 16 + l15];
        f32x4 acc[4][2];
        #pragma unroll
        for (int mf = 0; mf < 4; ++mf) {
            f32x4 z = {0.f, 0.f, 0.f, 0.f};
            acc[mf][0] = z; acc[mf][1] = z;
        }
        #pragma unroll
        for (int ks = 0; ks < 4; ++ks) {
            const int s = ct * 4 + ks;
            if (s < 126) stage(s + 2, bo2);
            // counted waits: tiles {s+1, s+2} stay in flight; never drain
            // to 0 mid-loop (T4)
            if (s < 126)      asm volatile("s_waitcnt vmcnt(8)" ::: "memory");
            else if (s == 126) asm volatile("s_waitcnt vmcnt(4)" ::: "memory");
            else               asm volatile("s_waitcnt vmcnt(0)" ::: "memory");
            __builtin_amdgcn_s_setprio(1);
            #pragma unroll
            for (int ks2 = 0; ks2 < 2; ++ks2) {
                const f16x8 b0 = *(const f16x8*)(wb + bo0 + boff[0][ks2]);
                const f16x8 b1 = *(const f16x8*)(wb + bo0 + boff[1][ks2]);
                #pragma unroll
                for (int mf = 0; mf < 4; ++mf) {
                    acc[mf][0] = __builtin_amdgcn_mfma_f32_16x16x32_f16(
                        a[mf][ks * 2 + ks2], b0, acc[mf][0], 0, 0, 0);
                    acc[mf][1] = __builtin_amdgcn_mfma_f32_16x16x32_f16(
                        a[mf][ks * 2 + ks2], b1, acc[mf][1], 0, 0, 0);
                }
            }
            __builtin_amdgcn_s_setprio(0);
            const int tmp = bo0; bo0 = bo1; bo1 = bo2; bo2 = tmp;
        }
        // epilogue: s = e2 - 2*dot, branchless top-2 per token-row
        const unsigned int cl0 = (unsigned int)(ct * 32 + l15);
        #pragma unroll
        for (int mf = 0; mf < 4; ++mf) {
            #pragma unroll
            for (int reg = 0; reg < 4; ++reg) {
                const int rr = mf * 4 + reg;
                const float sc0 = fmaf(-2.0f, acc[mf][0][reg], e2v0);
                const float sc1 = fmaf(-2.0f, acc[mf][1][reg], e2v1);
                if (fminf(sc0, sc1) < d2[rr]) {
                    {
                        const bool lt1 = sc0 < d1[rr], lt2 = sc0 < d2[rr];
                        const unsigned int ii = ipk[rr];
                        const unsigned int nif = (ii << 16) | cl0;
                        const unsigned int nis = (ii & 0xFFFFu) | (cl0 << 16);
                        d2[rr] = lt1 ? d1[rr] : (lt2 ? sc0 : d2[rr]);
                        ipk[rr] = lt1 ? nif : (lt2 ? nis : ii);
                        d1[rr] = lt1 ? sc0 : d1[rr];
                    }
                    {
                        const unsigned int cl1 = cl0 + 16;
                        const bool lt1 = sc1 < d1[rr], lt2 = sc1 < d2[rr];
                        const unsigned int ii = ipk[rr];
                        const unsigned int nif = (ii << 16) | cl1;
                        const unsigned int nis = (ii & 0xFFFFu) | (cl1 << 16);
                        d2[rr] = lt1 ? d1[rr] : (lt2 ? sc1 : d2[rr]);
                        ipk[rr] = lt1 ? nif : (lt2 ? nis : ii);
                        d1[rr] = lt1 ? sc1 : d1[rr];
                    }
                }
            }
        }
    }

    // pack (global code ids) + butterfly top-2 merge across the 16-lane group
    unsigned long long p1[16], p2[16];
    #pragma unroll
    for (int r = 0; r < 16; ++r) {
        p1[r] = (((unsigned long long)ford(d1[r])) << 32) |
                (unsigned int)(c0s + (ipk[r] & 0xFFFFu));
        p2[r] = (((unsigned long long)ford(d2[r])) << 32) |
                (unsigned int)(c0s + (ipk[r] >> 16));
    }
    #pragma unroll
    for (int st = 1; st < 16; st <<= 1) {
        #pragma unroll
        for (int r = 0; r < 16; ++r) {
            const unsigned long long q1 = __shfl_xor(p1[r], st, 64);
            const unsigned long long q2 = __shfl_xor(p2[r], st, 64);
            const unsigned long long n1 = p1[r] < q1 ? p1[r] : q1;
            const unsigned long long hi = p1[r] < q1 ? q1 : p1[r];
            const unsigned long long l2 = p2[r] < q2 ? p2[r] : q2;
            p1[r] = n1;
            p2[r] = hi < l2 ? hi : l2;
        }
    }
    // waves own disjoint rows -> direct global write, no LDS merge
    if (l15 == 0) {
        #pragma unroll
        for (int mf = 0; mf < 4; ++mf)
            #pragma unroll
            for (int reg = 0; reg < 4; ++reg) {
                const int n = rw + mf * 16 + lg * 4 + reg;
                unsigned int* cp = cand + (((size_t)n) << 4) + split * 2;
                cp[0] = (unsigned int)p1[mf * 4 + reg];
                cp[1] = (unsigned int)p2[mf * 4 + reg];
            }
    }
}

// exact f32 rescore of 16 candidates + gather + commit loss, fused.
// grid 512 blocks x 256 threads; 32 tokens/block (8 iters x 4 waves).
__global__ void vq_rescore_finalize(const float* __restrict__ xt, const float* __restrict__ embed,
                                    const float* __restrict__ e2,
                                    const unsigned int* __restrict__ cand,
                                    float* __restrict__ out, double* __restrict__ dsum) {
    __shared__ double red[4];
    const int tid = threadIdx.x, wid = tid >> 6, lane = tid & 63;
    double wsum = 0.0;
    #pragma unroll 1
    for (int it = 0; it < 8; ++it) {
        const int n = blockIdx.x * 32 + it * 4 + wid;
        const float4 xv = *(const float4*)(xt + (((size_t)n) << 8) + lane * 4);
        unsigned long long best = 0xFFFFFFFFFFFFFFFFull;
        #pragma unroll 2
        for (int j = 0; j < 16; ++j) {
            const unsigned int c = cand[(((size_t)n) << 4) + j];
            const float4 ev = *(const float4*)(embed + (((size_t)c) << 8) + lane * 4);
            float dt = xv.x * ev.x + xv.y * ev.y + xv.z * ev.z + xv.w * ev.w;
            #pragma unroll
            for (int off = 32; off > 0; off >>= 1) dt += __shfl_xor(dt, off, 64);
            const float s = fmaf(-2.0f, dt, e2[c]);
            const unsigned long long p = (((unsigned long long)ford(s)) << 32) | c;
            best = p < best ? p : best;
        }
        const unsigned int bi = (unsigned int)(best & 0xFFFFFFFFull);
        if (lane == 0) out[IND_OFF + n] = (float)bi;
        const float4 ev = *(const float4*)(embed + (((size_t)bi) << 8) + lane * 4);
        *(float4*)(out + Q_OFF + (((size_t)n) << 8) + lane * 4) = ev;
        const float q0 = ev.x - xv.x, q1 = ev.y - xv.y, q2 = ev.z - xv.z, q3 = ev.w - xv.w;
        float a4 = q0 * q0 + q1 * q1 + q2 * q2 + q3 * q3;
        #pragma unroll
        for (int off = 32; off > 0; off >>= 1) a4 += __shfl_xor(a4, off, 64);
        if (lane == 0) wsum += (double)a4;
    }
    if (lane == 0) red[wid] = wsum;
    __syncthreads();
    if (tid == 0) atomicAdd(dsum, red[0] + red[1] + red[2] + red[3]);
}

__global__ void vq_tail_kernel(const float* __restrict__ cs,
                               const double* __restrict__ dsum,
                               float* __restrict__ out) {
    __shared__ double red[4];
    const int tid = threadIdx.x;
    double s = 0.0;
    for (int i = tid; i < K; i += 256) {
        const float p = cs[i];
        s += (double)(p * logf(p + 1e-5f));
    }
    #pragma unroll
    for (int off = 32; off > 0; off >>= 1) s += __shfl_down(s, off, 64);
    if ((tid & 63) == 0) red[tid >> 6] = s;
    __syncthreads();
    if (tid == 0) {
        const double tot = red[0] + red[1] + red[2] + red[3];
        const double pv = exp(-tot);
        out[PERP_OFF] = (pv > 3.3e38) ? 3.3e38f : (float)pv;
        out[COMMIT_OFF] = (float)(*dsum * (1.0 / 4194304.0));
    }
}

// ============================ FALLBACK (ws too small) ============================
#define TM 64
#define TN 64
#define BKF 32
#define NSPLITF 2
#define CODES_PER_SPLIT (K / NSPLITF)
#define TILES_PER_SPLIT (CODES_PER_SPLIT / TN)

__global__ void vq_init_kernel(unsigned long long* __restrict__ keys, double* __restrict__ dsum) {
    int i = blockIdx.x * blockDim.x + threadIdx.x;
    if (i < N_TOK) keys[i] = 0xFFFFFFFFFFFFFFFFull;
    if (i == 0) *dsum = 0.0;
}
__global__ void vq_e2_kernel(const float* __restrict__ embed, float* __restrict__ e2) {
    int wave = threadIdx.x >> 6, lane = threadIdx.x & 63;
    int c = blockIdx.x * 4 + wave;
    const float4 v = *(const float4*)(embed + (size_t)c * D + lane * 4);
    float s = v.x * v.x + v.y * v.y + v.z * v.z + v.w * v.w;
    #pragma unroll
    for (int off = 32; off > 0; off >>= 1) s += __shfl_down(s, off, 64);
    if (lane == 0) e2[c] = s;
}
__global__ __launch_bounds__(256, 2) void vq_argmin_kernel(
    const float* __restrict__ x, const float* __restrict__ embed,
    const float* __restrict__ e2, unsigned long long* __restrict__ keys) {
    __shared__ float xT[D][TM];
    __shared__ float eT[BKF][TN + 4];
    const int tid = threadIdx.x;
    const int n0 = blockIdx.x * TM;
    const int b = n0 >> 10, p0 = n0 & 1023;
    const float* xb = x + (size_t)b * D * 1024 + p0;
    {
        const int t4 = (tid & 15) * 4, chb = tid >> 4;
        #pragma unroll
        for (int pass = 0; pass < 16; ++pass) {
            const int ch = pass * 16 + chb;
            *(float4*)&xT[ch][t4] = *(const float4*)(xb + (size_t)ch * 1024 + t4);
        }
    }
    __syncthreads();
    const int tm4 = (tid & 15) * 4, tn = tid >> 4, tn4 = tn * 4;
    float bestd[4]; int besti[4];
    #pragma unroll
    for (int i = 0; i < 4; ++i) { bestd[i] = INFINITY; besti[i] = 0x7fffffff; }
    for (int ct = 0; ct < TILES_PER_SPLIT; ++ct) {
        const int c0 = blockIdx.y * CODES_PER_SPLIT + ct * TN;
        float acc[4][4] = {};
        for (int kk = 0; kk < D; kk += BKF) {
            {
                const int j = tid >> 2, ch4 = (tid & 3) * 4;
                #pragma unroll
                for (int p = 0; p < 2; ++p) {
                    const int chl = p * 16 + ch4;
                    const float4 ev = *(const float4*)(embed + (size_t)(c0 + j) * D + kk + chl);
                    eT[chl + 0][j] = ev.x; eT[chl + 1][j] = ev.y;
                    eT[chl + 2][j] = ev.z; eT[chl + 3][j] = ev.w;
                }
            }
            __syncthreads();
            #pragma unroll
            for (int k2 = 0; k2 < BKF; ++k2) {
                const float4 a = *(const float4*)&xT[kk + k2][tm4];
                const float4 bv = *(const float4*)&eT[k2][tn4];
                acc[0][0] += a.x * bv.x; acc[0][1] += a.x * bv.y; acc[0][2] += a.x * bv.z; acc[0][3] += a.x * bv.w;
                acc[1][0] += a.y * bv.x; acc[1][1] += a.y * bv.y; acc[1][2] += a.y * bv.z; acc[1][3] += a.y * bv.w;
                acc[2][0] += a.z * bv.x; acc[2][1] += a.z * bv.y; acc[2][2] += a.z * bv.z; acc[2][3] += a.z * bv.w;
                acc[3][0] += a.w * bv.x; acc[3][1] += a.w * bv.y; acc[3][2] += a.w * bv.z; acc[3][3] += a.w * bv.w;
            }
            __syncthreads();
        }
        #pragma unroll
        for (int j = 0; j < 4; ++j) {
            const int c = c0 + tn4 + j;
            const float ec = e2[c];
            #pragma unroll
            for (int i = 0; i < 4; ++i) {
                const float s = ec - 2.0f * acc[i][j];
                if (s < bestd[i]) { bestd[i] = s; besti[i] = c; }
            }
        }
    }
    __syncthreads();
    float* cd = &eT[0][0];
    int* ci = (int*)&eT[16][0];
    #pragma unroll
    for (int i = 0; i < 4; ++i) { cd[tn * 64 + tm4 + i] = bestd[i]; ci[tn * 64 + tm4 + i] = besti[i]; }
    __syncthreads();
    if (tid < TM) {
        float bd = INFINITY; int bi = 0x7fffffff;
        for (int j = 0; j < 16; ++j) {
            const float d = cd[j * 64 + tid]; const int idx = ci[j * 64 + tid];
            if (d < bd || (d == bd && idx < bi)) { bd = d; bi = idx; }
        }
        atomicMin(&keys[n0 + tid], (((unsigned long long)ford(bd)) << 32) | (unsigned int)bi);
    }
}
__global__ void vq_finalize_kernel(const float* __restrict__ x, const float* __restrict__ embed,
                                   const unsigned long long* __restrict__ keys,
                                   float* __restrict__ out, double* __restrict__ dsum) {
    const int tid = threadIdx.x;
    const int n0 = blockIdx.x * 64;
    const int t = tid >> 2, q = tid & 3;
    const int n = n0 + t;
    const int b = n >> 10, p = n & 1023;
    if (tid < 64) {
        const int nn = n0 + tid;
        out[IND_OFF + nn] = (float)(int)(unsigned int)(keys[nn] & 0xFFFFFFFFull);
    }
    const int idx = (int)(unsigned int)(keys[n] & 0xFFFFFFFFull);
    const float* erow = embed + (size_t)idx * D;
    const float* xrow = x + (size_t)b * D * 1024 + p;
    float* qrow = out + Q_OFF + (size_t)n * D;
    float acc = 0.0f;
    #pragma unroll
    for (int i = 0; i < 16; ++i) {
        const int ch = i * 16 + q * 4;
        const float4 ev = *(const float4*)(erow + ch);
        *(float4*)(qrow + ch) = ev;
        const float x0 = xrow[(size_t)(ch + 0) * 1024];
        const float x1 = xrow[(size_t)(ch + 1) * 1024];
        const float x2 = xrow[(size_t)(ch + 2) * 1024];
        const float x3 = xrow[(size_t)(ch + 3) * 1024];
        const float d0 = ev.x - x0, d1 = ev.y - x1, d2 = ev.z - x2, d3 = ev.w - x3;
        acc += d0 * d0 + d1 * d1 + d2 * d2 + d3 * d3;
    }
    #pragma unroll
    for (int off = 32; off > 0; off >>= 1) acc += __shfl_down(acc, off, 64);
    if ((tid & 63) == 0) atomicAdd(dsum, (double)acc);
}

extern "C" void kernel_launch(void* const* d_in, const int* in_sizes, int n_in,
                              void* d_out, int out_size, void* d_ws, size_t ws_size,
                              hipStream_t stream) {
    const float* x = (const float*)d_in[0];
    const float* embed = (const float*)d_in[1];
    const float* cs = (const float*)d_in[2];
    float* out = (float*)d_out;
    char* ws = (char*)d_ws;

    if (ws_size >= (size_t)WS_NEED) {
        unsigned int* cand = (unsigned int*)(ws + WS_CAND);
        float* e2 = (float*)(ws + WS_E2);
        double* dsum = (double*)(ws + WS_DSUM);
        unsigned short* eh = (unsigned short*)(ws + WS_EH);
        unsigned short* xh = (unsigned short*)(ws + WS_XH);
        float* xt = (float*)(ws + WS_XT);

        vq_prep_e<<<dim3(K / 4), dim3(256), 0, stream>>>(embed, eh, e2, dsum);
        vq_convert_x<<<dim3(16, 4, 16), dim3(256), 0, stream>>>(x, xt, xh);
        vq_mfma_kernel<<<dim3(64, 8), dim3(256), 0, stream>>>(xh, eh, e2, cand);
        vq_rescore_finalize<<<dim3(512), dim3(256), 0, stream>>>(xt, embed, e2, cand, out, dsum);
        vq_tail_kernel<<<dim3(1), dim3(256), 0, stream>>>(cs, dsum, out);
    } else {
        unsigned long long* keys = (unsigned long long*)ws;
        float* e2 = (float*)(ws + 131072);
        double* dsum = (double*)(ws + 163840);
        vq_init_kernel<<<dim3(64), dim3(256), 0, stream>>>(keys, dsum);
        vq_e2_kernel<<<dim3(K / 4), dim3(256), 0, stream>>>(embed, e2);
        vq_argmin_kernel<<<dim3(N_TOK / TM, NSPLITF), dim3(256), 0, stream>>>(x, embed, e2, keys);
        vq_finalize_kernel<<<dim3(256), dim3(256), 0, stream>>>(x, embed, keys, out, dsum);
        vq_tail_kernel<<<dim3(1), dim3(256), 0, stream>>>(cs, dsum, out);
    }
}

// Round 8
// 196.402 us; speedup vs baseline: 1.0280x; 1.0280x over previous
//
#include <hip/hip_runtime.h>
#include <hip/hip_bf16.h>
#include <math.h>

typedef _Float16 f16x8 __attribute__((ext_vector_type(8)));
typedef float f32x4 __attribute__((ext_vector_type(4)));

#define N_TOK 16384
#define D 256
#define K 8192

#define Q_OFF 0
#define IND_OFF 4194304
#define PERP_OFF 4210688
#define COMMIT_OFF 4210689

// ---------- ws layout (bytes) ----------
#define WS_CAND   0u          // u32[16384][16]  (1 MB)
#define WS_E2     1048576u    // f32[8192]
#define WS_DSUM   1081344u    // double
#define WS_EH     1114112u    // f16[8192][256]  (4 MB)
#define WS_XH     5308416u    // f16[16384][256] (8 MB)
#define WS_XT     13697024u   // f32[16384][256] (16 MB)
#define WS_NEED   30474240u

__device__ __forceinline__ unsigned int ford(float f) {
    unsigned int u = __float_as_uint(f);
    return (u & 0x80000000u) ? ~u : (u | 0x80000000u);
}
__device__ __forceinline__ unsigned short f2h(float f) {
    _Float16 h = (_Float16)f;
    return *(unsigned short*)&h;
}
__device__ __forceinline__ void gload16(const void* g, void* l) {
    __builtin_amdgcn_global_load_lds(
        (const __attribute__((address_space(1))) unsigned int*)g,
        (__attribute__((address_space(3))) unsigned int*)l, 16, 0, 0);
}

// ============================ FAST PATH ============================

// transpose x: (b,c,p) f32 -> XT[n][c] f32 and Xh[n][c] f16
__global__ void vq_convert_x(const float* __restrict__ x, float* __restrict__ xt,
                             unsigned short* __restrict__ xh) {
    __shared__ float t[64][65];
    const int tid = threadIdx.x;
    const int p0 = blockIdx.x * 64, c0 = blockIdx.y * 64, b = blockIdx.z;
    const int q = tid & 15, h = tid >> 4;
    #pragma unroll
    for (int r = 0; r < 4; ++r) {
        const int cl = r * 16 + h;
        const float4 v = *(const float4*)(x + (((size_t)(b * 256 + c0 + cl)) << 10) + p0 + q * 4);
        t[cl][q * 4 + 0] = v.x; t[cl][q * 4 + 1] = v.y;
        t[cl][q * 4 + 2] = v.z; t[cl][q * 4 + 3] = v.w;
    }
    __syncthreads();
    #pragma unroll
    for (int r = 0; r < 4; ++r) {
        const int nl = r * 16 + h;
        const int n = (b << 10) + p0 + nl;
        const int c = c0 + q * 4;
        float4 vf; ushort4 vh;
        vf.x = t[q * 4 + 0][nl]; vf.y = t[q * 4 + 1][nl];
        vf.z = t[q * 4 + 2][nl]; vf.w = t[q * 4 + 3][nl];
        vh.x = f2h(vf.x); vh.y = f2h(vf.y); vh.z = f2h(vf.z); vh.w = f2h(vf.w);
        *(float4*)(xt + ((size_t)n << 8) + c) = vf;
        *(ushort4*)(xh + ((size_t)n << 8) + c) = vh;
    }
}

// fused: embed -> f16, e2 row norms, dsum init. one wave per code row.
__global__ void vq_prep_e(const float* __restrict__ e, unsigned short* __restrict__ eh,
                          float* __restrict__ e2, double* __restrict__ dsum) {
    if (blockIdx.x == 0 && threadIdx.x == 0) *dsum = 0.0;
    const int wave = threadIdx.x >> 6, lane = threadIdx.x & 63;
    const int c = blockIdx.x * 4 + wave;
    const float4 v = *(const float4*)(e + (size_t)c * D + lane * 4);
    ushort4 vh;
    vh.x = f2h(v.x); vh.y = f2h(v.y); vh.z = f2h(v.z); vh.w = f2h(v.w);
    *(ushort4*)(eh + (size_t)c * D + lane * 4) = vh;
    float s = v.x * v.x + v.y * v.y + v.z * v.z + v.w * v.w;
    #pragma unroll
    for (int off = 32; off > 0; off >>= 1) s += __shfl_down(s, off, 64);
    if (lane == 0) e2[c] = s;
}

// fp16 screen GEMM + per-split top-2.
// grid (64 M-tiles, 8 splits) = 512 blocks (2/CU), 256 threads (4 waves).
// A panel: 64 rows x 256 K per wave in REGISTERS (amdgpu_waves_per_eu(2,2)
// raises the regalloc budget to 256 VGPR so A actually stays resident).
// B: wave-PRIVATE LDS triple buffer, 3 x 4KB/wave; zero barriers in hot loop;
// ordering via counted s_waitcnt vmcnt (T3+T4). Staging addresses hoisted:
// per-lane offset is step-invariant, per-step tile offset is SALU-only.
__global__ __launch_bounds__(256)
__attribute__((amdgpu_waves_per_eu(2, 2)))
void vq_mfma_kernel(
    const unsigned short* __restrict__ xh, const unsigned short* __restrict__ eh,
    const float* __restrict__ e2, unsigned int* __restrict__ cand) {
    __shared__ __align__(16) unsigned short Bs[4][3][2048];  // 48 KB
    __shared__ float e2s[1024];                               // 4 KB

    const int tid = threadIdx.x;
    const int lane = tid & 63, wid = tid >> 6;
    const int l15 = lane & 15, lg = lane >> 4;
    const int split = blockIdx.y;
    const int m0 = blockIdx.x * 256;
    const int c0s = split * 1024;
    const int rw = m0 + wid * 64;  // wave's first token row
    char* wb = (char*)&Bs[wid][0][0];

    // e2 slice -> LDS (keeps vmcnt clean inside the hot loop)
    *(float4*)&e2s[tid * 4] = *(const float4*)(e2 + c0s + tid * 4);
    __syncthreads();

    // ---- A fragments: 64 rows x 256 K in registers (one-time global load) ----
    f16x8 a[4][8];
    #pragma unroll
    for (int mf = 0; mf < 4; ++mf) {
        const unsigned short* ap = xh + (((size_t)(rw + mf * 16 + l15)) << 8) + lg * 8;
        #pragma unroll
        for (int t = 0; t < 8; ++t)
            a[mf][t] = *(const f16x8*)(ap + t * 32);
    }
    // pin A in registers (also drains the A loads' vmcnt before staging starts)
    #pragma unroll
    for (int mf = 0; mf < 4; ++mf)
        #pragma unroll
        for (int t = 0; t < 8; ++t)
            asm volatile("" : "+v"(*(f32x4*)&a[mf][t]));

    // hoisted per-lane source offset (elements): row_local = lane>>3 (i adds 8/step),
    // col swizzle depends only on lane.
    const unsigned short* ebase =
        eh + (((size_t)c0s) << 8) + (((size_t)(lane >> 3)) << 8) +
        ((((lane & 7) ^ ((lane >> 3) & 7))) << 3);

    // stage tile s (32 codes x 64 k, 4KB) into this wave's buffer at offset bo.
    auto stage = [&](int s, int bo) {
        const int toff = ((s >> 2) << 13) + ((s & 3) << 6);  // element offset (uniform, SALU)
        const unsigned short* p = ebase + toff;
        #pragma unroll
        for (int i = 0; i < 4; ++i)
            gload16(p + (i << 11), wb + bo + i * 1024);
    };

    // B fragment read byte offsets (XOR-swizzled), relative to buffer base
    int boff[2][2];
    #pragma unroll
    for (int nf = 0; nf < 2; ++nf)
        #pragma unroll
        for (int ks2 = 0; ks2 < 2; ++ks2) {
            const int rb = nf * 16 + l15;
            boff[nf][ks2] = rb * 128 + (((ks2 * 4 + lg) ^ (rb & 7)) << 4);
        }

    float d1[16], d2[16];
    unsigned int ipk[16];
    #pragma unroll
    for (int r = 0; r < 16; ++r) { d1[r] = INFINITY; d2[r] = INFINITY; ipk[r] = 0; }

    int bo0 = 0, bo1 = 4096, bo2 = 8192;
    stage(0, bo0);
    stage(1, bo1);

    #pragma unroll 1
    for (int ct = 0; ct < 32; ++ct) {
        const float e2v0 = e2s[ct * 32 + l15];
        const float e2v1 = e2s[ct * 32 + 16 + l15];
        f32x4 acc[4][2];
        #pragma unroll
        for (int mf = 0; mf < 4; ++mf) {
            f32x4 z = {0.f, 0.f, 0.f, 0.f};
            acc[mf][0] = z; acc[mf][1] = z;
        }
        #pragma unroll
        for (int ks = 0; ks < 4; ++ks) {
            const int s = ct * 4 + ks;
            if (s < 126) stage(s + 2, bo2);
            // counted waits: tiles {s+1, s+2} stay in flight; never drain to 0
            // mid-loop (T4)
            if (s < 126)      asm volatile("s_waitcnt vmcnt(8)" ::: "memory");
            else if (s == 126) asm volatile("s_waitcnt vmcnt(4)" ::: "memory");
            else               asm volatile("s_waitcnt vmcnt(0)" ::: "memory");
            __builtin_amdgcn_s_setprio(1);
            #pragma unroll
            for (int ks2 = 0; ks2 < 2; ++ks2) {
                const f16x8 b0 = *(const f16x8*)(wb + bo0 + boff[0][ks2]);
                const f16x8 b1 = *(const f16x8*)(wb + bo0 + boff[1][ks2]);
                #pragma unroll
                for (int mf = 0; mf < 4; ++mf) {
                    acc[mf][0] = __builtin_amdgcn_mfma_f32_16x16x32_f16(
                        a[mf][ks * 2 + ks2], b0, acc[mf][0], 0, 0, 0);
                    acc[mf][1] = __builtin_amdgcn_mfma_f32_16x16x32_f16(
                        a[mf][ks * 2 + ks2], b1, acc[mf][1], 0, 0, 0);
                }
            }
            __builtin_amdgcn_s_setprio(0);
            const int tmp = bo0; bo0 = bo1; bo1 = bo2; bo2 = tmp;
        }
        // epilogue: s = e2 - 2*dot, branchless top-2 per token-row
        const unsigned int cl0 = (unsigned int)(ct * 32 + l15);
        #pragma unroll
        for (int mf = 0; mf < 4; ++mf) {
            #pragma unroll
            for (int reg = 0; reg < 4; ++reg) {
                const int rr = mf * 4 + reg;
                const float sc0 = fmaf(-2.0f, acc[mf][0][reg], e2v0);
                const float sc1 = fmaf(-2.0f, acc[mf][1][reg], e2v1);
                if (fminf(sc0, sc1) < d2[rr]) {
                    {
                        const bool lt1 = sc0 < d1[rr], lt2 = sc0 < d2[rr];
                        const unsigned int ii = ipk[rr];
                        const unsigned int nif = (ii << 16) | cl0;
                        const unsigned int nis = (ii & 0xFFFFu) | (cl0 << 16);
                        d2[rr] = lt1 ? d1[rr] : (lt2 ? sc0 : d2[rr]);
                        ipk[rr] = lt1 ? nif : (lt2 ? nis : ii);
                        d1[rr] = lt1 ? sc0 : d1[rr];
                    }
                    {
                        const unsigned int cl1 = cl0 + 16;
                        const bool lt1 = sc1 < d1[rr], lt2 = sc1 < d2[rr];
                        const unsigned int ii = ipk[rr];
                        const unsigned int nif = (ii << 16) | cl1;
                        const unsigned int nis = (ii & 0xFFFFu) | (cl1 << 16);
                        d2[rr] = lt1 ? d1[rr] : (lt2 ? sc1 : d2[rr]);
                        ipk[rr] = lt1 ? nif : (lt2 ? nis : ii);
                        d1[rr] = lt1 ? sc1 : d1[rr];
                    }
                }
            }
        }
    }

    // pack (global code ids) + butterfly top-2 merge across the 16-lane group
    unsigned long long p1[16], p2[16];
    #pragma unroll
    for (int r = 0; r < 16; ++r) {
        p1[r] = (((unsigned long long)ford(d1[r])) << 32) |
                (unsigned int)(c0s + (ipk[r] & 0xFFFFu));
        p2[r] = (((unsigned long long)ford(d2[r])) << 32) |
                (unsigned int)(c0s + (ipk[r] >> 16));
    }
    #pragma unroll
    for (int st = 1; st < 16; st <<= 1) {
        #pragma unroll
        for (int r = 0; r < 16; ++r) {
            const unsigned long long q1 = __shfl_xor(p1[r], st, 64);
            const unsigned long long q2 = __shfl_xor(p2[r], st, 64);
            const unsigned long long n1 = p1[r] < q1 ? p1[r] : q1;
            const unsigned long long hi = p1[r] < q1 ? q1 : p1[r];
            const unsigned long long l2 = p2[r] < q2 ? p2[r] : q2;
            p1[r] = n1;
            p2[r] = hi < l2 ? hi : l2;
        }
    }
    // waves own disjoint rows -> direct global write, no LDS merge
    if (l15 == 0) {
        #pragma unroll
        for (int mf = 0; mf < 4; ++mf)
            #pragma unroll
            for (int reg = 0; reg < 4; ++reg) {
                const int n = rw + mf * 16 + lg * 4 + reg;
                unsigned int* cp = cand + (((size_t)n) << 4) + split * 2;
                cp[0] = (unsigned int)p1[mf * 4 + reg];
                cp[1] = (unsigned int)p2[mf * 4 + reg];
            }
    }
}

// exact f32 rescore of 16 candidates + gather + commit loss, fused.
// grid 512 blocks x 256 threads; 32 tokens/block (8 iters x 4 waves).
__global__ void vq_rescore_finalize(const float* __restrict__ xt, const float* __restrict__ embed,
                                    const float* __restrict__ e2,
                                    const unsigned int* __restrict__ cand,
                                    float* __restrict__ out, double* __restrict__ dsum) {
    __shared__ double red[4];
    const int tid = threadIdx.x, wid = tid >> 6, lane = tid & 63;
    double wsum = 0.0;
    #pragma unroll 1
    for (int it = 0; it < 8; ++it) {
        const int n = blockIdx.x * 32 + it * 4 + wid;
        const float4 xv = *(const float4*)(xt + (((size_t)n) << 8) + lane * 4);
        unsigned long long best = 0xFFFFFFFFFFFFFFFFull;
        #pragma unroll 2
        for (int j = 0; j < 16; ++j) {
            const unsigned int c = cand[(((size_t)n) << 4) + j];
            const float4 ev = *(const float4*)(embed + (((size_t)c) << 8) + lane * 4);
            float dt = xv.x * ev.x + xv.y * ev.y + xv.z * ev.z + xv.w * ev.w;
            #pragma unroll
            for (int off = 32; off > 0; off >>= 1) dt += __shfl_xor(dt, off, 64);
            const float s = fmaf(-2.0f, dt, e2[c]);
            const unsigned long long p = (((unsigned long long)ford(s)) << 32) | c;
            best = p < best ? p : best;
        }
        const unsigned int bi = (unsigned int)(best & 0xFFFFFFFFull);
        if (lane == 0) out[IND_OFF + n] = (float)bi;
        const float4 ev = *(const float4*)(embed + (((size_t)bi) << 8) + lane * 4);
        *(float4*)(out + Q_OFF + (((size_t)n) << 8) + lane * 4) = ev;
        const float q0 = ev.x - xv.x, q1 = ev.y - xv.y, q2 = ev.z - xv.z, q3 = ev.w - xv.w;
        float a4 = q0 * q0 + q1 * q1 + q2 * q2 + q3 * q3;
        #pragma unroll
        for (int off = 32; off > 0; off >>= 1) a4 += __shfl_xor(a4, off, 64);
        if (lane == 0) wsum += (double)a4;
    }
    if (lane == 0) red[wid] = wsum;
    __syncthreads();
    if (tid == 0) atomicAdd(dsum, red[0] + red[1] + red[2] + red[3]);
}

__global__ void vq_tail_kernel(const float* __restrict__ cs,
                               const double* __restrict__ dsum,
                               float* __restrict__ out) {
    __shared__ double red[4];
    const int tid = threadIdx.x;
    double s = 0.0;
    for (int i = tid; i < K; i += 256) {
        const float p = cs[i];
        s += (double)(p * logf(p + 1e-5f));
    }
    #pragma unroll
    for (int off = 32; off > 0; off >>= 1) s += __shfl_down(s, off, 64);
    if ((tid & 63) == 0) red[tid >> 6] = s;
    __syncthreads();
    if (tid == 0) {
        const double tot = red[0] + red[1] + red[2] + red[3];
        const double pv = exp(-tot);
        out[PERP_OFF] = (pv > 3.3e38) ? 3.3e38f : (float)pv;
        out[COMMIT_OFF] = (float)(*dsum * (1.0 / 4194304.0));
    }
}

// ============================ FALLBACK (ws too small) ============================
#define TM 64
#define TN 64
#define BKF 32
#define NSPLITF 2
#define CODES_PER_SPLIT (K / NSPLITF)
#define TILES_PER_SPLIT (CODES_PER_SPLIT / TN)

__global__ void vq_init_kernel(unsigned long long* __restrict__ keys, double* __restrict__ dsum) {
    int i = blockIdx.x * blockDim.x + threadIdx.x;
    if (i < N_TOK) keys[i] = 0xFFFFFFFFFFFFFFFFull;
    if (i == 0) *dsum = 0.0;
}
__global__ void vq_e2_kernel(const float* __restrict__ embed, float* __restrict__ e2) {
    int wave = threadIdx.x >> 6, lane = threadIdx.x & 63;
    int c = blockIdx.x * 4 + wave;
    const float4 v = *(const float4*)(embed + (size_t)c * D + lane * 4);
    float s = v.x * v.x + v.y * v.y + v.z * v.z + v.w * v.w;
    #pragma unroll
    for (int off = 32; off > 0; off >>= 1) s += __shfl_down(s, off, 64);
    if (lane == 0) e2[c] = s;
}
__global__ __launch_bounds__(256, 2) void vq_argmin_kernel(
    const float* __restrict__ x, const float* __restrict__ embed,
    const float* __restrict__ e2, unsigned long long* __restrict__ keys) {
    __shared__ float xT[D][TM];
    __shared__ float eT[BKF][TN + 4];
    const int tid = threadIdx.x;
    const int n0 = blockIdx.x * TM;
    const int b = n0 >> 10, p0 = n0 & 1023;
    const float* xb = x + (size_t)b * D * 1024 + p0;
    {
        const int t4 = (tid & 15) * 4, chb = tid >> 4;
        #pragma unroll
        for (int pass = 0; pass < 16; ++pass) {
            const int ch = pass * 16 + chb;
            *(float4*)&xT[ch][t4] = *(const float4*)(xb + (size_t)ch * 1024 + t4);
        }
    }
    __syncthreads();
    const int tm4 = (tid & 15) * 4, tn = tid >> 4, tn4 = tn * 4;
    float bestd[4]; int besti[4];
    #pragma unroll
    for (int i = 0; i < 4; ++i) { bestd[i] = INFINITY; besti[i] = 0x7fffffff; }
    for (int ct = 0; ct < TILES_PER_SPLIT; ++ct) {
        const int c0 = blockIdx.y * CODES_PER_SPLIT + ct * TN;
        float acc[4][4] = {};
        for (int kk = 0; kk < D; kk += BKF) {
            {
                const int j = tid >> 2, ch4 = (tid & 3) * 4;
                #pragma unroll
                for (int p = 0; p < 2; ++p) {
                    const int chl = p * 16 + ch4;
                    const float4 ev = *(const float4*)(embed + (size_t)(c0 + j) * D + kk + chl);
                    eT[chl + 0][j] = ev.x; eT[chl + 1][j] = ev.y;
                    eT[chl + 2][j] = ev.z; eT[chl + 3][j] = ev.w;
                }
            }
            __syncthreads();
            #pragma unroll
            for (int k2 = 0; k2 < BKF; ++k2) {
                const float4 a = *(const float4*)&xT[kk + k2][tm4];
                const float4 bv = *(const float4*)&eT[k2][tn4];
                acc[0][0] += a.x * bv.x; acc[0][1] += a.x * bv.y; acc[0][2] += a.x * bv.z; acc[0][3] += a.x * bv.w;
                acc[1][0] += a.y * bv.x; acc[1][1] += a.y * bv.y; acc[1][2] += a.y * bv.z; acc[1][3] += a.y * bv.w;
                acc[2][0] += a.z * bv.x; acc[2][1] += a.z * bv.y; acc[2][2] += a.z * bv.z; acc[2][3] += a.z * bv.w;
                acc[3][0] += a.w * bv.x; acc[3][1] += a.w * bv.y; acc[3][2] += a.w * bv.z; acc[3][3] += a.w * bv.w;
            }
            __syncthreads();
        }
        #pragma unroll
        for (int j = 0; j < 4; ++j) {
            const int c = c0 + tn4 + j;
            const float ec = e2[c];
            #pragma unroll
            for (int i = 0; i < 4; ++i) {
                const float s = ec - 2.0f * acc[i][j];
                if (s < bestd[i]) { bestd[i] = s; besti[i] = c; }
            }
        }
    }
    __syncthreads();
    float* cd = &eT[0][0];
    int* ci = (int*)&eT[16][0];
    #pragma unroll
    for (int i = 0; i < 4; ++i) { cd[tn * 64 + tm4 + i] = bestd[i]; ci[tn * 64 + tm4 + i] = besti[i]; }
    __syncthreads();
    if (tid < TM) {
        float bd = INFINITY; int bi = 0x7fffffff;
        for (int j = 0; j < 16; ++j) {
            const float d = cd[j * 64 + tid]; const int idx = ci[j * 64 + tid];
            if (d < bd || (d == bd && idx < bi)) { bd = d; bi = idx; }
        }
        atomicMin(&keys[n0 + tid], (((unsigned long long)ford(bd)) << 32) | (unsigned int)bi);
    }
}
__global__ void vq_finalize_kernel(const float* __restrict__ x, const float* __restrict__ embed,
                                   const unsigned long long* __restrict__ keys,
                                   float* __restrict__ out, double* __restrict__ dsum) {
    const int tid = threadIdx.x;
    const int n0 = blockIdx.x * 64;
    const int t = tid >> 2, q = tid & 3;
    const int n = n0 + t;
    const int b = n >> 10, p = n & 1023;
    if (tid < 64) {
        const int nn = n0 + tid;
        out[IND_OFF + nn] = (float)(int)(unsigned int)(keys[nn] & 0xFFFFFFFFull);
    }
    const int idx = (int)(unsigned int)(keys[n] & 0xFFFFFFFFull);
    const float* erow = embed + (size_t)idx * D;
    const float* xrow = x + (size_t)b * D * 1024 + p;
    float* qrow = out + Q_OFF + (size_t)n * D;
    float acc = 0.0f;
    #pragma unroll
    for (int i = 0; i < 16; ++i) {
        const int ch = i * 16 + q * 4;
        const float4 ev = *(const float4*)(erow + ch);
        *(float4*)(qrow + ch) = ev;
        const float x0 = xrow[(size_t)(ch + 0) * 1024];
        const float x1 = xrow[(size_t)(ch + 1) * 1024];
        const float x2 = xrow[(size_t)(ch + 2) * 1024];
        const float x3 = xrow[(size_t)(ch + 3) * 1024];
        const float d0 = ev.x - x0, d1 = ev.y - x1, d2 = ev.z - x2, d3 = ev.w - x3;
        acc += d0 * d0 + d1 * d1 + d2 * d2 + d3 * d3;
    }
    #pragma unroll
    for (int off = 32; off > 0; off >>= 1) acc += __shfl_down(acc, off, 64);
    if ((tid & 63) == 0) atomicAdd(dsum, (double)acc);
}

extern "C" void kernel_launch(void* const* d_in, const int* in_sizes, int n_in,
                              void* d_out, int out_size, void* d_ws, size_t ws_size,
                              hipStream_t stream) {
    const float* x = (const float*)d_in[0];
    const float* embed = (const float*)d_in[1];
    const float* cs = (const float*)d_in[2];
    float* out = (float*)d_out;
    char* ws = (char*)d_ws;

    if (ws_size >= (size_t)WS_NEED) {
        unsigned int* cand = (unsigned int*)(ws + WS_CAND);
        float* e2 = (float*)(ws + WS_E2);
        double* dsum = (double*)(ws + WS_DSUM);
        unsigned short* eh = (unsigned short*)(ws + WS_EH);
        unsigned short* xh = (unsigned short*)(ws + WS_XH);
        float* xt = (float*)(ws + WS_XT);

        vq_prep_e<<<dim3(K / 4), dim3(256), 0, stream>>>(embed, eh, e2, dsum);
        vq_convert_x<<<dim3(16, 4, 16), dim3(256), 0, stream>>>(x, xt, xh);
        vq_mfma_kernel<<<dim3(64, 8), dim3(256), 0, stream>>>(xh, eh, e2, cand);
        vq_rescore_finalize<<<dim3(512), dim3(256), 0, stream>>>(xt, embed, e2, cand, out, dsum);
        vq_tail_kernel<<<dim3(1), dim3(256), 0, stream>>>(cs, dsum, out);
    } else {
        unsigned long long* keys = (unsigned long long*)ws;
        float* e2 = (float*)(ws + 131072);
        double* dsum = (double*)(ws + 163840);
        vq_init_kernel<<<dim3(64), dim3(256), 0, stream>>>(keys, dsum);
        vq_e2_kernel<<<dim3(K / 4), dim3(256), 0, stream>>>(embed, e2);
        vq_argmin_kernel<<<dim3(N_TOK / TM, NSPLITF), dim3(256), 0, stream>>>(x, embed, e2, keys);
        vq_finalize_kernel<<<dim3(256), dim3(256), 0, stream>>>(x, embed, keys, out, dsum);
        vq_tail_kernel<<<dim3(1), dim3(256), 0, stream>>>(cs, dsum, out);
    }
}

// Round 9
// 173.222 us; speedup vs baseline: 1.1655x; 1.1338x over previous
//
#include <hip/hip_runtime.h>
#include <hip/hip_bf16.h>
#include <math.h>

typedef _Float16 f16x8 __attribute__((ext_vector_type(8)));
typedef float f32x4 __attribute__((ext_vector_type(4)));

#define N_TOK 16384
#define D 256
#define K 8192

#define Q_OFF 0
#define IND_OFF 4194304
#define PERP_OFF 4210688
#define COMMIT_OFF 4210689

// ---------- ws layout (bytes) ----------
#define WS_CAND   0u          // u32[16384][16]  (1 MB)
#define WS_E2     1048576u    // f32[8192]
#define WS_DSUM   1081344u    // double
#define WS_EH     1114112u    // f16[8192][256]  (4 MB)
#define WS_XH     5308416u    // f16[16384][256] (8 MB)
#define WS_XT     13697024u   // f32[16384][256] (16 MB)
#define WS_NEED   30474240u

__device__ __forceinline__ unsigned int ford(float f) {
    unsigned int u = __float_as_uint(f);
    return (u & 0x80000000u) ? ~u : (u | 0x80000000u);
}
__device__ __forceinline__ unsigned short f2h(float f) {
    _Float16 h = (_Float16)f;
    return *(unsigned short*)&h;
}
__device__ __forceinline__ void gload16(const void* g, void* l) {
    __builtin_amdgcn_global_load_lds(
        (const __attribute__((address_space(1))) unsigned int*)g,
        (__attribute__((address_space(3))) unsigned int*)l, 16, 0, 0);
}

// ============================ FAST PATH ============================

// transpose x: (b,c,p) f32 -> XT[n][c] f32 and Xh[n][c] f16
__global__ void vq_convert_x(const float* __restrict__ x, float* __restrict__ xt,
                             unsigned short* __restrict__ xh) {
    __shared__ float t[64][65];
    const int tid = threadIdx.x;
    const int p0 = blockIdx.x * 64, c0 = blockIdx.y * 64, b = blockIdx.z;
    const int q = tid & 15, h = tid >> 4;
    #pragma unroll
    for (int r = 0; r < 4; ++r) {
        const int cl = r * 16 + h;
        const float4 v = *(const float4*)(x + (((size_t)(b * 256 + c0 + cl)) << 10) + p0 + q * 4);
        t[cl][q * 4 + 0] = v.x; t[cl][q * 4 + 1] = v.y;
        t[cl][q * 4 + 2] = v.z; t[cl][q * 4 + 3] = v.w;
    }
    __syncthreads();
    #pragma unroll
    for (int r = 0; r < 4; ++r) {
        const int nl = r * 16 + h;
        const int n = (b << 10) + p0 + nl;
        const int c = c0 + q * 4;
        float4 vf; ushort4 vh;
        vf.x = t[q * 4 + 0][nl]; vf.y = t[q * 4 + 1][nl];
        vf.z = t[q * 4 + 2][nl]; vf.w = t[q * 4 + 3][nl];
        vh.x = f2h(vf.x); vh.y = f2h(vf.y); vh.z = f2h(vf.z); vh.w = f2h(vf.w);
        *(float4*)(xt + ((size_t)n << 8) + c) = vf;
        *(ushort4*)(xh + ((size_t)n << 8) + c) = vh;
    }
}

// fused: embed -> f16, e2 row norms, dsum init. one wave per code row.
__global__ void vq_prep_e(const float* __restrict__ e, unsigned short* __restrict__ eh,
                          float* __restrict__ e2, double* __restrict__ dsum) {
    if (blockIdx.x == 0 && threadIdx.x == 0) *dsum = 0.0;
    const int wave = threadIdx.x >> 6, lane = threadIdx.x & 63;
    const int c = blockIdx.x * 4 + wave;
    const float4 v = *(const float4*)(e + (size_t)c * D + lane * 4);
    ushort4 vh;
    vh.x = f2h(v.x); vh.y = f2h(v.y); vh.z = f2h(v.z); vh.w = f2h(v.w);
    *(ushort4*)(eh + (size_t)c * D + lane * 4) = vh;
    float s = v.x * v.x + v.y * v.y + v.z * v.z + v.w * v.w;
    #pragma unroll
    for (int off = 32; off > 0; off >>= 1) s += __shfl_down(s, off, 64);
    if (lane == 0) e2[c] = s;
}

// fp16 screen GEMM + per-split top-2.
// grid (64 M-tiles, 8 splits) = 512 blocks (2/CU), 256 threads (4 waves).
// A: 64 rows x 256 K per wave in registers/AGPRs (pinned).
// B: COOPERATIVE triple-buffered full-K tiles (32 codes x 256 k = 16KB each);
// staged ONCE per block (no per-wave duplication). One raw s_barrier + counted
// vmcnt per 64 MFMAs (T3+T4).
__global__ __launch_bounds__(256)
__attribute__((amdgpu_waves_per_eu(2, 2)))
void vq_mfma_kernel(
    const unsigned short* __restrict__ xh, const unsigned short* __restrict__ eh,
    const float* __restrict__ e2, unsigned int* __restrict__ cand) {
    __shared__ __align__(16) unsigned short Bs[3][32 * 256];  // 48 KB
    __shared__ float e2s[1024];                               // 4 KB

    const int tid = threadIdx.x;
    const int lane = tid & 63, wid = tid >> 6;
    const int l15 = lane & 15, lg = lane >> 4;
    const int split = blockIdx.y;
    const int m0 = blockIdx.x * 256;
    const int c0s = split * 1024;
    const int rw = m0 + wid * 64;  // wave's first token row

    // e2 slice -> LDS (keeps vmcnt clean inside the hot loop)
    *(float4*)&e2s[tid * 4] = *(const float4*)(e2 + c0s + tid * 4);

    // ---- A fragments: 64 rows x 256 K in registers (one-time global load) ----
    f16x8 a[4][8];
    #pragma unroll
    for (int mf = 0; mf < 4; ++mf) {
        const unsigned short* ap = xh + (((size_t)(rw + mf * 16 + l15)) << 8) + lg * 8;
        #pragma unroll
        for (int t = 0; t < 8; ++t)
            a[mf][t] = *(const f16x8*)(ap + t * 32);
    }
    // pin A (forces the loads' vmcnt drained here, before pipeline counting)
    #pragma unroll
    for (int mf = 0; mf < 4; ++mf)
        #pragma unroll
        for (int t = 0; t < 8; ++t)
            asm volatile("" : "+v"(*(f32x4*)&a[mf][t]));

    __syncthreads();  // e2s visible; full drain (prologue only)

    // cooperative staging geometry: thread stages chunks {i*256+tid}, i=0..3.
    // chunk -> code row r = chunk>>5 (r&7 invariant in i), k-chunk c = chunk&31.
    // source col pre-swizzled, LDS linear (rule #21).
    const int r0 = tid >> 5, cc = tid & 31;
    const unsigned short* ebase =
        eh + (((size_t)(c0s + r0)) << 8) + ((cc ^ (r0 & 7)) << 3);
    char* wdst = (char*)Bs + tid * 16;

    auto stage = [&](int t, int bo) {
        const unsigned short* p = ebase + t * 8192;  // t*32 codes * 256 k
        #pragma unroll
        for (int i = 0; i < 4; ++i)
            gload16(p + i * 2048, wdst + bo + i * 4096);
    };

    // B fragment read helpers (XOR-swizzled): row rb = nf*16+l15, byte =
    // rb*512 + ((kc ^ (l15&7))<<4), kc = ks*8+ks2*4+lg.
    const int rb0 = l15 * 512;
    const int rb1 = rb0 + 16 * 512;
    const int rx = l15 & 7;
    const char* wb = (const char*)Bs;

    float d1[16], d2[16];
    unsigned int ipk[16];
    #pragma unroll
    for (int r = 0; r < 16; ++r) { d1[r] = INFINITY; d2[r] = INFINITY; ipk[r] = 0; }

    int bo0 = 0, bo1 = 16384, bo2 = 32768;
    stage(0, bo0);
    stage(1, bo1);

    #pragma unroll 1
    for (int t = 0; t < 32; ++t) {
        // counted wait: tile t landed, tile t+1 stays in flight (T4)
        if (t < 31) asm volatile("s_waitcnt vmcnt(4)" ::: "memory");
        else        asm volatile("s_waitcnt vmcnt(0)" ::: "memory");
        __builtin_amdgcn_s_barrier();  // all threads' tile-t chunks in LDS
        if (t < 30) stage(t + 2, bo2); // overwrites buf last read at iter t-1

        const float e2v0 = e2s[t * 32 + l15];
        const float e2v1 = e2s[t * 32 + 16 + l15];
        f32x4 acc[4][2];
        #pragma unroll
        for (int mf = 0; mf < 4; ++mf) {
            f32x4 z = {0.f, 0.f, 0.f, 0.f};
            acc[mf][0] = z; acc[mf][1] = z;
        }
        __builtin_amdgcn_s_setprio(1);
        #pragma unroll
        for (int ks = 0; ks < 4; ++ks) {
            #pragma unroll
            for (int ks2 = 0; ks2 < 2; ++ks2) {
                const int kc = ks * 8 + ks2 * 4;  // + lg at runtime
                const int ko = ((kc + lg) ^ rx) << 4;
                const f16x8 b0 = *(const f16x8*)(wb + bo0 + rb0 + ko);
                const f16x8 b1 = *(const f16x8*)(wb + bo0 + rb1 + ko);
                #pragma unroll
                for (int mf = 0; mf < 4; ++mf) {
                    acc[mf][0] = __builtin_amdgcn_mfma_f32_16x16x32_f16(
                        a[mf][ks * 2 + ks2], b0, acc[mf][0], 0, 0, 0);
                    acc[mf][1] = __builtin_amdgcn_mfma_f32_16x16x32_f16(
                        a[mf][ks * 2 + ks2], b1, acc[mf][1], 0, 0, 0);
                }
            }
        }
        __builtin_amdgcn_s_setprio(0);

        // epilogue: s = e2 - 2*dot, branchless top-2 per token-row
        const unsigned int cl0 = (unsigned int)(t * 32 + l15);
        #pragma unroll
        for (int mf = 0; mf < 4; ++mf) {
            #pragma unroll
            for (int reg = 0; reg < 4; ++reg) {
                const int rr = mf * 4 + reg;
                const float sc0 = fmaf(-2.0f, acc[mf][0][reg], e2v0);
                const float sc1 = fmaf(-2.0f, acc[mf][1][reg], e2v1);
                if (fminf(sc0, sc1) < d2[rr]) {
                    {
                        const bool lt1 = sc0 < d1[rr], lt2 = sc0 < d2[rr];
                        const unsigned int ii = ipk[rr];
                        const unsigned int nif = (ii << 16) | cl0;
                        const unsigned int nis = (ii & 0xFFFFu) | (cl0 << 16);
                        d2[rr] = lt1 ? d1[rr] : (lt2 ? sc0 : d2[rr]);
                        ipk[rr] = lt1 ? nif : (lt2 ? nis : ii);
                        d1[rr] = lt1 ? sc0 : d1[rr];
                    }
                    {
                        const unsigned int cl1 = cl0 + 16;
                        const bool lt1 = sc1 < d1[rr], lt2 = sc1 < d2[rr];
                        const unsigned int ii = ipk[rr];
                        const unsigned int nif = (ii << 16) | cl1;
                        const unsigned int nis = (ii & 0xFFFFu) | (cl1 << 16);
                        d2[rr] = lt1 ? d1[rr] : (lt2 ? sc1 : d2[rr]);
                        ipk[rr] = lt1 ? nif : (lt2 ? nis : ii);
                        d1[rr] = lt1 ? sc1 : d1[rr];
                    }
                }
            }
        }
        const int tmp = bo0; bo0 = bo1; bo1 = bo2; bo2 = tmp;
    }

    // pack (global code ids) + butterfly top-2 merge across the 16-lane group
    unsigned long long p1[16], p2[16];
    #pragma unroll
    for (int r = 0; r < 16; ++r) {
        p1[r] = (((unsigned long long)ford(d1[r])) << 32) |
                (unsigned int)(c0s + (ipk[r] & 0xFFFFu));
        p2[r] = (((unsigned long long)ford(d2[r])) << 32) |
                (unsigned int)(c0s + (ipk[r] >> 16));
    }
    #pragma unroll
    for (int st = 1; st < 16; st <<= 1) {
        #pragma unroll
        for (int r = 0; r < 16; ++r) {
            const unsigned long long q1 = __shfl_xor(p1[r], st, 64);
            const unsigned long long q2 = __shfl_xor(p2[r], st, 64);
            const unsigned long long n1 = p1[r] < q1 ? p1[r] : q1;
            const unsigned long long hi = p1[r] < q1 ? q1 : p1[r];
            const unsigned long long l2 = p2[r] < q2 ? p2[r] : q2;
            p1[r] = n1;
            p2[r] = hi < l2 ? hi : l2;
        }
    }
    // waves own disjoint rows -> direct global write, no LDS merge
    if (l15 == 0) {
        #pragma unroll
        for (int mf = 0; mf < 4; ++mf)
            #pragma unroll
            for (int reg = 0; reg < 4; ++reg) {
                const int n = rw + mf * 16 + lg * 4 + reg;
                unsigned int* cp = cand + (((size_t)n) << 4) + split * 2;
                cp[0] = (unsigned int)p1[mf * 4 + reg];
                cp[1] = (unsigned int)p2[mf * 4 + reg];
            }
    }
}

// exact f32 rescore of 16 candidates + gather + commit loss, fused.
// grid 512 blocks x 256 threads; 32 tokens/block (8 iters x 4 waves).
__global__ void vq_rescore_finalize(const float* __restrict__ xt, const float* __restrict__ embed,
                                    const float* __restrict__ e2,
                                    const unsigned int* __restrict__ cand,
                                    float* __restrict__ out, double* __restrict__ dsum) {
    __shared__ double red[4];
    const int tid = threadIdx.x, wid = tid >> 6, lane = tid & 63;
    double wsum = 0.0;
    #pragma unroll 1
    for (int it = 0; it < 8; ++it) {
        const int n = blockIdx.x * 32 + it * 4 + wid;
        const float4 xv = *(const float4*)(xt + (((size_t)n) << 8) + lane * 4);
        unsigned long long best = 0xFFFFFFFFFFFFFFFFull;
        #pragma unroll 2
        for (int j = 0; j < 16; ++j) {
            const unsigned int c = cand[(((size_t)n) << 4) + j];
            const float4 ev = *(const float4*)(embed + (((size_t)c) << 8) + lane * 4);
            float dt = xv.x * ev.x + xv.y * ev.y + xv.z * ev.z + xv.w * ev.w;
            #pragma unroll
            for (int off = 32; off > 0; off >>= 1) dt += __shfl_xor(dt, off, 64);
            const float s = fmaf(-2.0f, dt, e2[c]);
            const unsigned long long p = (((unsigned long long)ford(s)) << 32) | c;
            best = p < best ? p : best;
        }
        const unsigned int bi = (unsigned int)(best & 0xFFFFFFFFull);
        if (lane == 0) out[IND_OFF + n] = (float)bi;
        const float4 ev = *(const float4*)(embed + (((size_t)bi) << 8) + lane * 4);
        *(float4*)(out + Q_OFF + (((size_t)n) << 8) + lane * 4) = ev;
        const float q0 = ev.x - xv.x, q1 = ev.y - xv.y, q2 = ev.z - xv.z, q3 = ev.w - xv.w;
        float a4 = q0 * q0 + q1 * q1 + q2 * q2 + q3 * q3;
        #pragma unroll
        for (int off = 32; off > 0; off >>= 1) a4 += __shfl_xor(a4, off, 64);
        if (lane == 0) wsum += (double)a4;
    }
    if (lane == 0) red[wid] = wsum;
    __syncthreads();
    if (tid == 0) atomicAdd(dsum, red[0] + red[1] + red[2] + red[3]);
}

__global__ void vq_tail_kernel(const float* __restrict__ cs,
                               const double* __restrict__ dsum,
                               float* __restrict__ out) {
    __shared__ double red[4];
    const int tid = threadIdx.x;
    double s = 0.0;
    for (int i = tid; i < K; i += 256) {
        const float p = cs[i];
        s += (double)(p * logf(p + 1e-5f));
    }
    #pragma unroll
    for (int off = 32; off > 0; off >>= 1) s += __shfl_down(s, off, 64);
    if ((tid & 63) == 0) red[tid >> 6] = s;
    __syncthreads();
    if (tid == 0) {
        const double tot = red[0] + red[1] + red[2] + red[3];
        const double pv = exp(-tot);
        out[PERP_OFF] = (pv > 3.3e38) ? 3.3e38f : (float)pv;
        out[COMMIT_OFF] = (float)(*dsum * (1.0 / 4194304.0));
    }
}

// ============================ FALLBACK (ws too small) ============================
#define TM 64
#define TN 64
#define BKF 32
#define NSPLITF 2
#define CODES_PER_SPLIT (K / NSPLITF)
#define TILES_PER_SPLIT (CODES_PER_SPLIT / TN)

__global__ void vq_init_kernel(unsigned long long* __restrict__ keys, double* __restrict__ dsum) {
    int i = blockIdx.x * blockDim.x + threadIdx.x;
    if (i < N_TOK) keys[i] = 0xFFFFFFFFFFFFFFFFull;
    if (i == 0) *dsum = 0.0;
}
__global__ void vq_e2_kernel(const float* __restrict__ embed, float* __restrict__ e2) {
    int wave = threadIdx.x >> 6, lane = threadIdx.x & 63;
    int c = blockIdx.x * 4 + wave;
    const float4 v = *(const float4*)(embed + (size_t)c * D + lane * 4);
    float s = v.x * v.x + v.y * v.y + v.z * v.z + v.w * v.w;
    #pragma unroll
    for (int off = 32; off > 0; off >>= 1) s += __shfl_down(s, off, 64);
    if (lane == 0) e2[c] = s;
}
__global__ __launch_bounds__(256, 2) void vq_argmin_kernel(
    const float* __restrict__ x, const float* __restrict__ embed,
    const float* __restrict__ e2, unsigned long long* __restrict__ keys) {
    __shared__ float xT[D][TM];
    __shared__ float eT[BKF][TN + 4];
    const int tid = threadIdx.x;
    const int n0 = blockIdx.x * TM;
    const int b = n0 >> 10, p0 = n0 & 1023;
    const float* xb = x + (size_t)b * D * 1024 + p0;
    {
        const int t4 = (tid & 15) * 4, chb = tid >> 4;
        #pragma unroll
        for (int pass = 0; pass < 16; ++pass) {
            const int ch = pass * 16 + chb;
            *(float4*)&xT[ch][t4] = *(const float4*)(xb + (size_t)ch * 1024 + t4);
        }
    }
    __syncthreads();
    const int tm4 = (tid & 15) * 4, tn = tid >> 4, tn4 = tn * 4;
    float bestd[4]; int besti[4];
    #pragma unroll
    for (int i = 0; i < 4; ++i) { bestd[i] = INFINITY; besti[i] = 0x7fffffff; }
    for (int ct = 0; ct < TILES_PER_SPLIT; ++ct) {
        const int c0 = blockIdx.y * CODES_PER_SPLIT + ct * TN;
        float acc[4][4] = {};
        for (int kk = 0; kk < D; kk += BKF) {
            {
                const int j = tid >> 2, ch4 = (tid & 3) * 4;
                #pragma unroll
                for (int p = 0; p < 2; ++p) {
                    const int chl = p * 16 + ch4;
                    const float4 ev = *(const float4*)(embed + (size_t)(c0 + j) * D + kk + chl);
                    eT[chl + 0][j] = ev.x; eT[chl + 1][j] = ev.y;
                    eT[chl + 2][j] = ev.z; eT[chl + 3][j] = ev.w;
                }
            }
            __syncthreads();
            #pragma unroll
            for (int k2 = 0; k2 < BKF; ++k2) {
                const float4 a = *(const float4*)&xT[kk + k2][tm4];
                const float4 bv = *(const float4*)&eT[k2][tn4];
                acc[0][0] += a.x * bv.x; acc[0][1] += a.x * bv.y; acc[0][2] += a.x * bv.z; acc[0][3] += a.x * bv.w;
                acc[1][0] += a.y * bv.x; acc[1][1] += a.y * bv.y; acc[1][2] += a.y * bv.z; acc[1][3] += a.y * bv.w;
                acc[2][0] += a.z * bv.x; acc[2][1] += a.z * bv.y; acc[2][2] += a.z * bv.z; acc[2][3] += a.z * bv.w;
                acc[3][0] += a.w * bv.x; acc[3][1] += a.w * bv.y; acc[3][2] += a.w * bv.z; acc[3][3] += a.w * bv.w;
            }
            __syncthreads();
        }
        #pragma unroll
        for (int j = 0; j < 4; ++j) {
            const int c = c0 + tn4 + j;
            const float ec = e2[c];
            #pragma unroll
            for (int i = 0; i < 4; ++i) {
                const float s = ec - 2.0f * acc[i][j];
                if (s < bestd[i]) { bestd[i] = s; besti[i] = c; }
            }
        }
    }
    __syncthreads();
    float* cd = &eT[0][0];
    int* ci = (int*)&eT[16][0];
    #pragma unroll
    for (int i = 0; i < 4; ++i) { cd[tn * 64 + tm4 + i] = bestd[i]; ci[tn * 64 + tm4 + i] = besti[i]; }
    __syncthreads();
    if (tid < TM) {
        float bd = INFINITY; int bi = 0x7fffffff;
        for (int j = 0; j < 16; ++j) {
            const float d = cd[j * 64 + tid]; const int idx = ci[j * 64 + tid];
            if (d < bd || (d == bd && idx < bi)) { bd = d; bi = idx; }
        }
        atomicMin(&keys[n0 + tid], (((unsigned long long)ford(bd)) << 32) | (unsigned int)bi);
    }
}
__global__ void vq_finalize_kernel(const float* __restrict__ x, const float* __restrict__ embed,
                                   const unsigned long long* __restrict__ keys,
                                   float* __restrict__ out, double* __restrict__ dsum) {
    const int tid = threadIdx.x;
    const int n0 = blockIdx.x * 64;
    const int t = tid >> 2, q = tid & 3;
    const int n = n0 + t;
    const int b = n >> 10, p = n & 1023;
    if (tid < 64) {
        const int nn = n0 + tid;
        out[IND_OFF + nn] = (float)(int)(unsigned int)(keys[nn] & 0xFFFFFFFFull);
    }
    const int idx = (int)(unsigned int)(keys[n] & 0xFFFFFFFFull);
    const float* erow = embed + (size_t)idx * D;
    const float* xrow = x + (size_t)b * D * 1024 + p;
    float* qrow = out + Q_OFF + (size_t)n * D;
    float acc = 0.0f;
    #pragma unroll
    for (int i = 0; i < 16; ++i) {
        const int ch = i * 16 + q * 4;
        const float4 ev = *(const float4*)(erow + ch);
        *(float4*)(qrow + ch) = ev;
        const float x0 = xrow[(size_t)(ch + 0) * 1024];
        const float x1 = xrow[(size_t)(ch + 1) * 1024];
        const float x2 = xrow[(size_t)(ch + 2) * 1024];
        const float x3 = xrow[(size_t)(ch + 3) * 1024];
        const float d0 = ev.x - x0, d1 = ev.y - x1, d2 = ev.z - x2, d3 = ev.w - x3;
        acc += d0 * d0 + d1 * d1 + d2 * d2 + d3 * d3;
    }
    #pragma unroll
    for (int off = 32; off > 0; off >>= 1) acc += __shfl_down(acc, off, 64);
    if ((tid & 63) == 0) atomicAdd(dsum, (double)acc);
}

extern "C" void kernel_launch(void* const* d_in, const int* in_sizes, int n_in,
                              void* d_out, int out_size, void* d_ws, size_t ws_size,
                              hipStream_t stream) {
    const float* x = (const float*)d_in[0];
    const float* embed = (const float*)d_in[1];
    const float* cs = (const float*)d_in[2];
    float* out = (float*)d_out;
    char* ws = (char*)d_ws;

    if (ws_size >= (size_t)WS_NEED) {
        unsigned int* cand = (unsigned int*)(ws + WS_CAND);
        float* e2 = (float*)(ws + WS_E2);
        double* dsum = (double*)(ws + WS_DSUM);
        unsigned short* eh = (unsigned short*)(ws + WS_EH);
        unsigned short* xh = (unsigned short*)(ws + WS_XH);
        float* xt = (float*)(ws + WS_XT);

        vq_prep_e<<<dim3(K / 4), dim3(256), 0, stream>>>(embed, eh, e2, dsum);
        vq_convert_x<<<dim3(16, 4, 16), dim3(256), 0, stream>>>(x, xt, xh);
        vq_mfma_kernel<<<dim3(64, 8), dim3(256), 0, stream>>>(xh, eh, e2, cand);
        vq_rescore_finalize<<<dim3(512), dim3(256), 0, stream>>>(xt, embed, e2, cand, out, dsum);
        vq_tail_kernel<<<dim3(1), dim3(256), 0, stream>>>(cs, dsum, out);
    } else {
        unsigned long long* keys = (unsigned long long*)ws;
        float* e2 = (float*)(ws + 131072);
        double* dsum = (double*)(ws + 163840);
        vq_init_kernel<<<dim3(64), dim3(256), 0, stream>>>(keys, dsum);
        vq_e2_kernel<<<dim3(K / 4), dim3(256), 0, stream>>>(embed, e2);
        vq_argmin_kernel<<<dim3(N_TOK / TM, NSPLITF), dim3(256), 0, stream>>>(x, embed, e2, keys);
        vq_finalize_kernel<<<dim3(256), dim3(256), 0, stream>>>(x, embed, keys, out, dsum);
        vq_tail_kernel<<<dim3(1), dim3(256), 0, stream>>>(cs, dsum, out);
    }
}

// Round 10
// 167.577 us; speedup vs baseline: 1.2048x; 1.0337x over previous
//
#include <hip/hip_runtime.h>
#include <hip/hip_bf16.h>
#include <math.h>

typedef _Float16 f16x8 __attribute__((ext_vector_type(8)));
typedef float f32x4 __attribute__((ext_vector_type(4)));

#define N_TOK 16384
#define D 256
#define K 8192

#define Q_OFF 0
#define IND_OFF 4194304
#define PERP_OFF 4210688
#define COMMIT_OFF 4210689

// ---------- ws layout (bytes) ----------
#define WS_CAND   0u          // u32[16384][16]  (1 MB)
#define WS_E2     1048576u    // f32[8192]
#define WS_DSUM   1081344u    // double
#define WS_EH     1114112u    // f16[8192][256]  (4 MB)
#define WS_XH     5308416u    // f16[16384][256] (8 MB)
#define WS_XT     13697024u   // f32[16384][256] (16 MB)
#define WS_NEED   30474240u

__device__ __forceinline__ unsigned int ford(float f) {
    unsigned int u = __float_as_uint(f);
    return (u & 0x80000000u) ? ~u : (u | 0x80000000u);
}
__device__ __forceinline__ unsigned short f2h(float f) {
    _Float16 h = (_Float16)f;
    return *(unsigned short*)&h;
}
__device__ __forceinline__ void gload16(const void* g, void* l) {
    __builtin_amdgcn_global_load_lds(
        (const __attribute__((address_space(1))) unsigned int*)g,
        (__attribute__((address_space(3))) unsigned int*)l, 16, 0, 0);
}

// ============================ FAST PATH ============================

// transpose x: (b,c,p) f32 -> XT[n][c] f32 and Xh[n][c] f16
__global__ void vq_convert_x(const float* __restrict__ x, float* __restrict__ xt,
                             unsigned short* __restrict__ xh) {
    __shared__ float t[64][65];
    const int tid = threadIdx.x;
    const int p0 = blockIdx.x * 64, c0 = blockIdx.y * 64, b = blockIdx.z;
    const int q = tid & 15, h = tid >> 4;
    #pragma unroll
    for (int r = 0; r < 4; ++r) {
        const int cl = r * 16 + h;
        const float4 v = *(const float4*)(x + (((size_t)(b * 256 + c0 + cl)) << 10) + p0 + q * 4);
        t[cl][q * 4 + 0] = v.x; t[cl][q * 4 + 1] = v.y;
        t[cl][q * 4 + 2] = v.z; t[cl][q * 4 + 3] = v.w;
    }
    __syncthreads();
    #pragma unroll
    for (int r = 0; r < 4; ++r) {
        const int nl = r * 16 + h;
        const int n = (b << 10) + p0 + nl;
        const int c = c0 + q * 4;
        float4 vf; ushort4 vh;
        vf.x = t[q * 4 + 0][nl]; vf.y = t[q * 4 + 1][nl];
        vf.z = t[q * 4 + 2][nl]; vf.w = t[q * 4 + 3][nl];
        vh.x = f2h(vf.x); vh.y = f2h(vf.y); vh.z = f2h(vf.z); vh.w = f2h(vf.w);
        *(float4*)(xt + ((size_t)n << 8) + c) = vf;
        *(ushort4*)(xh + ((size_t)n << 8) + c) = vh;
    }
}

// fused: embed -> f16, e2 row norms, dsum init. one wave per code row.
__global__ void vq_prep_e(const float* __restrict__ e, unsigned short* __restrict__ eh,
                          float* __restrict__ e2, double* __restrict__ dsum) {
    if (blockIdx.x == 0 && threadIdx.x == 0) *dsum = 0.0;
    const int wave = threadIdx.x >> 6, lane = threadIdx.x & 63;
    const int c = blockIdx.x * 4 + wave;
    const float4 v = *(const float4*)(e + (size_t)c * D + lane * 4);
    ushort4 vh;
    vh.x = f2h(v.x); vh.y = f2h(v.y); vh.z = f2h(v.z); vh.w = f2h(v.w);
    *(ushort4*)(eh + (size_t)c * D + lane * 4) = vh;
    float s = v.x * v.x + v.y * v.y + v.z * v.z + v.w * v.w;
    #pragma unroll
    for (int off = 32; off > 0; off >>= 1) s += __shfl_down(s, off, 64);
    if (lane == 0) e2[c] = s;
}

// fp16 screen GEMM + per-split top-2.
// grid (64 M-tiles, 8 splits) = 512 blocks (2/CU), 256 threads (4 waves).
// A: 64 rows x 256 K per wave in registers/AGPRs (pinned).
// B: cooperative double-buffered 64-code x 256-k tiles (32KB each); 16 iters,
// one barrier each; free vmcnt(0) (stage issued a full iter earlier).
// Inner loop: 2-deep B-pair software pipeline (reads for pair p+1 issued
// before pair p's MFMAs) with all LDS read addressing folded into ds_read
// immediate offsets (outer unroll-2 makes buffer offset compile-time).
__global__ __launch_bounds__(256)
__attribute__((amdgpu_waves_per_eu(2, 2)))
void vq_mfma_kernel(
    const unsigned short* __restrict__ xh, const unsigned short* __restrict__ eh,
    const float* __restrict__ e2, unsigned int* __restrict__ cand) {
    __shared__ __align__(16) unsigned short Bs[2][64 * 256];  // 64 KB
    __shared__ float e2s[1024];                               // 4 KB

    const int tid = threadIdx.x;
    const int lane = tid & 63, wid = tid >> 6;
    const int l15 = lane & 15, lg = lane >> 4;
    const int split = blockIdx.y;
    const int m0 = blockIdx.x * 256;
    const int c0s = split * 1024;
    const int rw = m0 + wid * 64;  // wave's first token row

    // e2 slice -> LDS (keeps vmcnt clean inside the hot loop)
    *(float4*)&e2s[tid * 4] = *(const float4*)(e2 + c0s + tid * 4);

    // ---- A fragments: 64 rows x 256 K in registers (one-time global load) ----
    f16x8 a[4][8];
    #pragma unroll
    for (int mf = 0; mf < 4; ++mf) {
        const unsigned short* ap = xh + (((size_t)(rw + mf * 16 + l15)) << 8) + lg * 8;
        #pragma unroll
        for (int t = 0; t < 8; ++t)
            a[mf][t] = *(const f16x8*)(ap + t * 32);
    }
    // pin A (forces the loads' vmcnt drained here, before pipeline counting)
    #pragma unroll
    for (int mf = 0; mf < 4; ++mf)
        #pragma unroll
        for (int t = 0; t < 8; ++t)
            asm volatile("" : "+v"(*(f32x4*)&a[mf][t]));

    __syncthreads();  // e2s visible

    // cooperative staging: 8 chunks/thread; row r = i*8 + (tid>>5) so r&7 =
    // tid>>5 is i-invariant; source col pre-swizzled, LDS linear (rule #21).
    const int r0 = tid >> 5, cc = tid & 31;
    const unsigned short* ebase =
        eh + (((size_t)(c0s + r0)) << 8) + ((cc ^ r0) << 3);
    char* wdst = (char*)Bs + tid * 16;
    auto stage = [&](int t, int bo) {
        const unsigned short* p = ebase + t * 16384;  // t*64 codes * 256 k
        #pragma unroll
        for (int i = 0; i < 8; ++i)
            gload16(p + i * 2048, wdst + bo + i * 4096);
    };

    // per-lane read bases: row stride 512B, XOR-swizzled k-chunk per pair.
    // addr = rbase + ko[pr]  (+ compile-time offset: buf | s2*16384 | nf*8192)
    const char* rbase = (const char*)Bs + l15 * 512;
    int ko[8];
    #pragma unroll
    for (int pr = 0; pr < 8; ++pr) ko[pr] = (((4 * pr + lg) ^ (l15 & 7)) << 4);

    float d1[16], d2[16];
    unsigned int ipk[16];
    #pragma unroll
    for (int r = 0; r < 16; ++r) { d1[r] = INFINITY; d2[r] = INFINITY; ipk[r] = 0; }

    stage(0, 0);

    #pragma unroll 2
    for (int t = 0; t < 16; ++t) {
        asm volatile("s_waitcnt vmcnt(0)" ::: "memory");  // free: issued 1 iter ago
        __builtin_amdgcn_s_barrier();                     // tile t fully in LDS
        if (t < 15) stage(t + 1, ((t + 1) & 1) * 32768);  // other buffer

        const int BUF = (t & 1) * 32768;  // compile-time per unrolled copy
        #pragma unroll
        for (int s2 = 0; s2 < 2; ++s2) {
            const int sb = BUF + s2 * 16384;
            const float e2v0 = e2s[t * 64 + s2 * 32 + l15];
            const float e2v1 = e2s[t * 64 + s2 * 32 + 16 + l15];
            f32x4 acc[4][2];
            #pragma unroll
            for (int mf = 0; mf < 4; ++mf) {
                f32x4 z = {0.f, 0.f, 0.f, 0.f};
                acc[mf][0] = z; acc[mf][1] = z;
            }
            // 2-deep pair pipeline: reads for pair pr+1 in flight during pr's MFMAs
            f16x8 b0a = *(const f16x8*)(rbase + ko[0] + sb);
            f16x8 b1a = *(const f16x8*)(rbase + ko[0] + sb + 8192);
            #pragma unroll
            for (int pr = 0; pr < 8; ++pr) {
                f16x8 b0n, b1n;
                if (pr < 7) {
                    b0n = *(const f16x8*)(rbase + ko[pr + 1] + sb);
                    b1n = *(const f16x8*)(rbase + ko[pr + 1] + sb + 8192);
                }
                #pragma unroll
                for (int mf = 0; mf < 4; ++mf) {
                    acc[mf][0] = __builtin_amdgcn_mfma_f32_16x16x32_f16(
                        a[mf][pr], b0a, acc[mf][0], 0, 0, 0);
                    acc[mf][1] = __builtin_amdgcn_mfma_f32_16x16x32_f16(
                        a[mf][pr], b1a, acc[mf][1], 0, 0, 0);
                }
                b0a = b0n; b1a = b1n;  // static rotation (unrolled -> SSA)
            }
            // epilogue: s = e2 - 2*dot, branchless top-2 per token-row
            const unsigned int cl0 = (unsigned int)(t * 64 + s2 * 32 + l15);
            #pragma unroll
            for (int mf = 0; mf < 4; ++mf) {
                #pragma unroll
                for (int reg = 0; reg < 4; ++reg) {
                    const int rr = mf * 4 + reg;
                    const float sc0 = fmaf(-2.0f, acc[mf][0][reg], e2v0);
                    const float sc1 = fmaf(-2.0f, acc[mf][1][reg], e2v1);
                    if (fminf(sc0, sc1) < d2[rr]) {
                        {
                            const bool lt1 = sc0 < d1[rr], lt2 = sc0 < d2[rr];
                            const unsigned int ii = ipk[rr];
                            const unsigned int nif = (ii << 16) | cl0;
                            const unsigned int nis = (ii & 0xFFFFu) | (cl0 << 16);
                            d2[rr] = lt1 ? d1[rr] : (lt2 ? sc0 : d2[rr]);
                            ipk[rr] = lt1 ? nif : (lt2 ? nis : ii);
                            d1[rr] = lt1 ? sc0 : d1[rr];
                        }
                        {
                            const unsigned int cl1 = cl0 + 16;
                            const bool lt1 = sc1 < d1[rr], lt2 = sc1 < d2[rr];
                            const unsigned int ii = ipk[rr];
                            const unsigned int nif = (ii << 16) | cl1;
                            const unsigned int nis = (ii & 0xFFFFu) | (cl1 << 16);
                            d2[rr] = lt1 ? d1[rr] : (lt2 ? sc1 : d2[rr]);
                            ipk[rr] = lt1 ? nif : (lt2 ? nis : ii);
                            d1[rr] = lt1 ? sc1 : d1[rr];
                        }
                    }
                }
            }
        }
    }

    // pack (global code ids) + butterfly top-2 merge across the 16-lane group
    unsigned long long p1[16], p2[16];
    #pragma unroll
    for (int r = 0; r < 16; ++r) {
        p1[r] = (((unsigned long long)ford(d1[r])) << 32) |
                (unsigned int)(c0s + (ipk[r] & 0xFFFFu));
        p2[r] = (((unsigned long long)ford(d2[r])) << 32) |
                (unsigned int)(c0s + (ipk[r] >> 16));
    }
    #pragma unroll
    for (int st = 1; st < 16; st <<= 1) {
        #pragma unroll
        for (int r = 0; r < 16; ++r) {
            const unsigned long long q1 = __shfl_xor(p1[r], st, 64);
            const unsigned long long q2 = __shfl_xor(p2[r], st, 64);
            const unsigned long long n1 = p1[r] < q1 ? p1[r] : q1;
            const unsigned long long hi = p1[r] < q1 ? q1 : p1[r];
            const unsigned long long l2 = p2[r] < q2 ? p2[r] : q2;
            p1[r] = n1;
            p2[r] = hi < l2 ? hi : l2;
        }
    }
    // waves own disjoint rows -> direct global write, no LDS merge
    if (l15 == 0) {
        #pragma unroll
        for (int mf = 0; mf < 4; ++mf)
            #pragma unroll
            for (int reg = 0; reg < 4; ++reg) {
                const int n = rw + mf * 16 + lg * 4 + reg;
                unsigned int* cp = cand + (((size_t)n) << 4) + split * 2;
                cp[0] = (unsigned int)p1[mf * 4 + reg];
                cp[1] = (unsigned int)p2[mf * 4 + reg];
            }
    }
}

// exact f32 rescore of 16 candidates + gather + commit loss, fused.
// grid 512 blocks x 256 threads; 32 tokens/block (8 iters x 4 waves).
__global__ void vq_rescore_finalize(const float* __restrict__ xt, const float* __restrict__ embed,
                                    const float* __restrict__ e2,
                                    const unsigned int* __restrict__ cand,
                                    float* __restrict__ out, double* __restrict__ dsum) {
    __shared__ double red[4];
    const int tid = threadIdx.x, wid = tid >> 6, lane = tid & 63;
    double wsum = 0.0;
    #pragma unroll 1
    for (int it = 0; it < 8; ++it) {
        const int n = blockIdx.x * 32 + it * 4 + wid;
        const float4 xv = *(const float4*)(xt + (((size_t)n) << 8) + lane * 4);
        unsigned long long best = 0xFFFFFFFFFFFFFFFFull;
        #pragma unroll 2
        for (int j = 0; j < 16; ++j) {
            const unsigned int c = cand[(((size_t)n) << 4) + j];
            const float4 ev = *(const float4*)(embed + (((size_t)c) << 8) + lane * 4);
            float dt = xv.x * ev.x + xv.y * ev.y + xv.z * ev.z + xv.w * ev.w;
            #pragma unroll
            for (int off = 32; off > 0; off >>= 1) dt += __shfl_xor(dt, off, 64);
            const float s = fmaf(-2.0f, dt, e2[c]);
            const unsigned long long p = (((unsigned long long)ford(s)) << 32) | c;
            best = p < best ? p : best;
        }
        const unsigned int bi = (unsigned int)(best & 0xFFFFFFFFull);
        if (lane == 0) out[IND_OFF + n] = (float)bi;
        const float4 ev = *(const float4*)(embed + (((size_t)bi) << 8) + lane * 4);
        *(float4*)(out + Q_OFF + (((size_t)n) << 8) + lane * 4) = ev;
        const float q0 = ev.x - xv.x, q1 = ev.y - xv.y, q2 = ev.z - xv.z, q3 = ev.w - xv.w;
        float a4 = q0 * q0 + q1 * q1 + q2 * q2 + q3 * q3;
        #pragma unroll
        for (int off = 32; off > 0; off >>= 1) a4 += __shfl_xor(a4, off, 64);
        if (lane == 0) wsum += (double)a4;
    }
    if (lane == 0) red[wid] = wsum;
    __syncthreads();
    if (tid == 0) atomicAdd(dsum, red[0] + red[1] + red[2] + red[3]);
}

__global__ void vq_tail_kernel(const float* __restrict__ cs,
                               const double* __restrict__ dsum,
                               float* __restrict__ out) {
    __shared__ double red[4];
    const int tid = threadIdx.x;
    double s = 0.0;
    for (int i = tid; i < K; i += 256) {
        const float p = cs[i];
        s += (double)(p * logf(p + 1e-5f));
    }
    #pragma unroll
    for (int off = 32; off > 0; off >>= 1) s += __shfl_down(s, off, 64);
    if ((tid & 63) == 0) red[tid >> 6] = s;
    __syncthreads();
    if (tid == 0) {
        const double tot = red[0] + red[1] + red[2] + red[3];
        const double pv = exp(-tot);
        out[PERP_OFF] = (pv > 3.3e38) ? 3.3e38f : (float)pv;
        out[COMMIT_OFF] = (float)(*dsum * (1.0 / 4194304.0));
    }
}

// ============================ FALLBACK (ws too small) ============================
#define TM 64
#define TN 64
#define BKF 32
#define NSPLITF 2
#define CODES_PER_SPLIT (K / NSPLITF)
#define TILES_PER_SPLIT (CODES_PER_SPLIT / TN)

__global__ void vq_init_kernel(unsigned long long* __restrict__ keys, double* __restrict__ dsum) {
    int i = blockIdx.x * blockDim.x + threadIdx.x;
    if (i < N_TOK) keys[i] = 0xFFFFFFFFFFFFFFFFull;
    if (i == 0) *dsum = 0.0;
}
__global__ void vq_e2_kernel(const float* __restrict__ embed, float* __restrict__ e2) {
    int wave = threadIdx.x >> 6, lane = threadIdx.x & 63;
    int c = blockIdx.x * 4 + wave;
    const float4 v = *(const float4*)(embed + (size_t)c * D + lane * 4);
    float s = v.x * v.x + v.y * v.y + v.z * v.z + v.w * v.w;
    #pragma unroll
    for (int off = 32; off > 0; off >>= 1) s += __shfl_down(s, off, 64);
    if (lane == 0) e2[c] = s;
}
__global__ __launch_bounds__(256, 2) void vq_argmin_kernel(
    const float* __restrict__ x, const float* __restrict__ embed,
    const float* __restrict__ e2, unsigned long long* __restrict__ keys) {
    __shared__ float xT[D][TM];
    __shared__ float eT[BKF][TN + 4];
    const int tid = threadIdx.x;
    const int n0 = blockIdx.x * TM;
    const int b = n0 >> 10, p0 = n0 & 1023;
    const float* xb = x + (size_t)b * D * 1024 + p0;
    {
        const int t4 = (tid & 15) * 4, chb = tid >> 4;
        #pragma unroll
        for (int pass = 0; pass < 16; ++pass) {
            const int ch = pass * 16 + chb;
            *(float4*)&xT[ch][t4] = *(const float4*)(xb + (size_t)ch * 1024 + t4);
        }
    }
    __syncthreads();
    const int tm4 = (tid & 15) * 4, tn = tid >> 4, tn4 = tn * 4;
    float bestd[4]; int besti[4];
    #pragma unroll
    for (int i = 0; i < 4; ++i) { bestd[i] = INFINITY; besti[i] = 0x7fffffff; }
    for (int ct = 0; ct < TILES_PER_SPLIT; ++ct) {
        const int c0 = blockIdx.y * CODES_PER_SPLIT + ct * TN;
        float acc[4][4] = {};
        for (int kk = 0; kk < D; kk += BKF) {
            {
                const int j = tid >> 2, ch4 = (tid & 3) * 4;
                #pragma unroll
                for (int p = 0; p < 2; ++p) {
                    const int chl = p * 16 + ch4;
                    const float4 ev = *(const float4*)(embed + (size_t)(c0 + j) * D + kk + chl);
                    eT[chl + 0][j] = ev.x; eT[chl + 1][j] = ev.y;
                    eT[chl + 2][j] = ev.z; eT[chl + 3][j] = ev.w;
                }
            }
            __syncthreads();
            #pragma unroll
            for (int k2 = 0; k2 < BKF; ++k2) {
                const float4 a = *(const float4*)&xT[kk + k2][tm4];
                const float4 bv = *(const float4*)&eT[k2][tn4];
                acc[0][0] += a.x * bv.x; acc[0][1] += a.x * bv.y; acc[0][2] += a.x * bv.z; acc[0][3] += a.x * bv.w;
                acc[1][0] += a.y * bv.x; acc[1][1] += a.y * bv.y; acc[1][2] += a.y * bv.z; acc[1][3] += a.y * bv.w;
                acc[2][0] += a.z * bv.x; acc[2][1] += a.z * bv.y; acc[2][2] += a.z * bv.z; acc[2][3] += a.z * bv.w;
                acc[3][0] += a.w * bv.x; acc[3][1] += a.w * bv.y; acc[3][2] += a.w * bv.z; acc[3][3] += a.w * bv.w;
            }
            __syncthreads();
        }
        #pragma unroll
        for (int j = 0; j < 4; ++j) {
            const int c = c0 + tn4 + j;
            const float ec = e2[c];
            #pragma unroll
            for (int i = 0; i < 4; ++i) {
                const float s = ec - 2.0f * acc[i][j];
                if (s < bestd[i]) { bestd[i] = s; besti[i] = c; }
            }
        }
    }
    __syncthreads();
    float* cd = &eT[0][0];
    int* ci = (int*)&eT[16][0];
    #pragma unroll
    for (int i = 0; i < 4; ++i) { cd[tn * 64 + tm4 + i] = bestd[i]; ci[tn * 64 + tm4 + i] = besti[i]; }
    __syncthreads();
    if (tid < TM) {
        float bd = INFINITY; int bi = 0x7fffffff;
        for (int j = 0; j < 16; ++j) {
            const float d = cd[j * 64 + tid]; const int idx = ci[j * 64 + tid];
            if (d < bd || (d == bd && idx < bi)) { bd = d; bi = idx; }
        }
        atomicMin(&keys[n0 + tid], (((unsigned long long)ford(bd)) << 32) | (unsigned int)bi);
    }
}
__global__ void vq_finalize_kernel(const float* __restrict__ x, const float* __restrict__ embed,
                                   const unsigned long long* __restrict__ keys,
                                   float* __restrict__ out, double* __restrict__ dsum) {
    const int tid = threadIdx.x;
    const int n0 = blockIdx.x * 64;
    const int t = tid >> 2, q = tid & 3;
    const int n = n0 + t;
    const int b = n >> 10, p = n & 1023;
    if (tid < 64) {
        const int nn = n0 + tid;
        out[IND_OFF + nn] = (float)(int)(unsigned int)(keys[nn] & 0xFFFFFFFFull);
    }
    const int idx = (int)(unsigned int)(keys[n] & 0xFFFFFFFFull);
    const float* erow = embed + (size_t)idx * D;
    const float* xrow = x + (size_t)b * D * 1024 + p;
    float* qrow = out + Q_OFF + (size_t)n * D;
    float acc = 0.0f;
    #pragma unroll
    for (int i = 0; i < 16; ++i) {
        const int ch = i * 16 + q * 4;
        const float4 ev = *(const float4*)(erow + ch);
        *(float4*)(qrow + ch) = ev;
        const float x0 = xrow[(size_t)(ch + 0) * 1024];
        const float x1 = xrow[(size_t)(ch + 1) * 1024];
        const float x2 = xrow[(size_t)(ch + 2) * 1024];
        const float x3 = xrow[(size_t)(ch + 3) * 1024];
        const float d0 = ev.x - x0, d1 = ev.y - x1, d2 = ev.z - x2, d3 = ev.w - x3;
        acc += d0 * d0 + d1 * d1 + d2 * d2 + d3 * d3;
    }
    #pragma unroll
    for (int off = 32; off > 0; off >>= 1) acc += __shfl_down(acc, off, 64);
    if ((tid & 63) == 0) atomicAdd(dsum, (double)acc);
}

extern "C" void kernel_launch(void* const* d_in, const int* in_sizes, int n_in,
                              void* d_out, int out_size, void* d_ws, size_t ws_size,
                              hipStream_t stream) {
    const float* x = (const float*)d_in[0];
    const float* embed = (const float*)d_in[1];
    const float* cs = (const float*)d_in[2];
    float* out = (float*)d_out;
    char* ws = (char*)d_ws;

    if (ws_size >= (size_t)WS_NEED) {
        unsigned int* cand = (unsigned int*)(ws + WS_CAND);
        float* e2 = (float*)(ws + WS_E2);
        double* dsum = (double*)(ws + WS_DSUM);
        unsigned short* eh = (unsigned short*)(ws + WS_EH);
        unsigned short* xh = (unsigned short*)(ws + WS_XH);
        float* xt = (float*)(ws + WS_XT);

        vq_prep_e<<<dim3(K / 4), dim3(256), 0, stream>>>(embed, eh, e2, dsum);
        vq_convert_x<<<dim3(16, 4, 16), dim3(256), 0, stream>>>(x, xt, xh);
        vq_mfma_kernel<<<dim3(64, 8), dim3(256), 0, stream>>>(xh, eh, e2, cand);
        vq_rescore_finalize<<<dim3(512), dim3(256), 0, stream>>>(xt, embed, e2, cand, out, dsum);
        vq_tail_kernel<<<dim3(1), dim3(256), 0, stream>>>(cs, dsum, out);
    } else {
        unsigned long long* keys = (unsigned long long*)ws;
        float* e2 = (float*)(ws + 131072);
        double* dsum = (double*)(ws + 163840);
        vq_init_kernel<<<dim3(64), dim3(256), 0, stream>>>(keys, dsum);
        vq_e2_kernel<<<dim3(K / 4), dim3(256), 0, stream>>>(embed, e2);
        vq_argmin_kernel<<<dim3(N_TOK / TM, NSPLITF), dim3(256), 0, stream>>>(x, embed, e2, keys);
        vq_finalize_kernel<<<dim3(256), dim3(256), 0, stream>>>(x, embed, keys, out, dsum);
        vq_tail_kernel<<<dim3(1), dim3(256), 0, stream>>>(cs, dsum, out);
    }
}